// Round 1
// baseline (17475.307 us; speedup 1.0000x reference)
//
#include <hip/hip_runtime.h>
#include <hip/hip_fp16.h>
#include <stdint.h>

#define B_  64
#define T_  512
#define H1_ 257

// ---------------- wave-level helpers (64-lane, 4 elems/lane: i = lane + 64*e) ---------

__device__ __forceinline__ float wsum(float v) {
#pragma unroll
  for (int m = 32; m; m >>= 1) v += __shfl_xor(v, m, 64);
  return v;
}

__device__ __forceinline__ float sq4(const float* s) {
  return wsum(s[0]*s[0] + s[1]*s[1] + s[2]*s[2] + s[3]*s[3]);
}
__device__ __forceinline__ float dot4(const float* a, const float* b) {
  return wsum(a[0]*b[0] + a[1]*b[1] + a[2]*b[2] + a[3]*b[3]);
}

// logmap0(x)[1:]  (first component of result is 0 and never needed)
__device__ __forceinline__ void logmap0_(float x0, const float* s, float sqrtK, float* o) {
  float yn = fmaxf(sqrtf(sq4(s)), 1e-15f);
  float th = fmaxf(x0 / sqrtK, 1.0f + 1e-7f);
  float c  = sqrtK * acoshf(th) / yn;
#pragma unroll
  for (int e = 0; e < 4; ++e) o[e] = c * s[e];
}

// expmap0 from spatial tangent, fused with proj (proj recomputes the 0-component)
__device__ __forceinline__ void expmap0_(const float* u, float K, float sqrtK,
                                         float& x0, float* s) {
  float sn = fmaxf(sqrtf(sq4(u)), 1e-15f);
  float th = sn / sqrtK;
  float c  = sqrtK * sinhf(th) / sn;
#pragma unroll
  for (int e = 0; e < 4; ++e) s[e] = c * u[e];
  x0 = sqrtf(fmaxf(K + sq4(s), 1e-7f));
}

// X <- proj(expmap(proj_tan(ptransp0-core(X, lm)), X))
// lm plays the role of logmap0(Y) (0 first component). Exactly mirrors reference
// mobius_add / (ptransp0 + expmap) including every clip.
__device__ __forceinline__ void madd_(float& x0, float* xs, const float* lm,
                                      float K, float sqrtK) {
  float ynx = fmaxf(sqrtf(sq4(xs)), 1e-15f);
  float inv = 1.0f / ynx;
  float yh[4];
#pragma unroll
  for (int e = 0; e < 4; ++e) yh[e] = xs[e] * inv;
  float alpha = dot4(yh, lm) / sqrtK;
  float c2 = alpha * (sqrtK - x0);
  float w[4];
#pragma unroll
  for (int e = 0; e < 4; ++e) w[e] = lm[e] - c2 * yh[e];
  float ux = dot4(xs, w);                  // proj_tan: recompute 0-component
  float w0 = ux / fmaxf(x0, 1e-7f);
  float md = sq4(w) - w0 * w0;             // mink_dot(u,u) = sum(s^2) - u0^2
  float mn = sqrtf(fmaxf(md, 1e-7f));
  float th = fmaxf(fminf(mn, 1e6f) / sqrtK, 1e-15f);
  float ch = coshf(th);
  float shot = sinhf(th) / th;
  float rs[4];
#pragma unroll
  for (int e = 0; e < 4; ++e) rs[e] = ch * xs[e] + shot * w[e];
  x0 = sqrtf(fmaxf(K + sq4(rs), 1e-7f));   // proj
#pragma unroll
  for (int e = 0; e < 4; ++e) xs[e] = rs[e];
}

// ---------------- kernel T: transpose + f16-pack weights ----------------
// Col layout [z | r | h] (gate source indices: z<-2, r<-0, h<-1 for both ih and hh).
// Packed over input-dim pairs: OUT[i2][col] = half2( W[row, 1+2*i2], W[row, 1+2*i2+1] ),
// row = gsrc*257 + 1 + j.
__global__ void pack_weights(const float* __restrict__ wih, const float* __restrict__ whh,
                             uint32_t* __restrict__ UT2, uint32_t* __restrict__ WT2) {
  int idx = blockIdx.x * 256 + threadIdx.x;        // 0 .. 196607
  int m   = idx / 98304;
  int rem = idx % 98304;
  int i2  = rem / 768;
  int col = rem % 768;
  int g   = col >> 8;
  int j   = col & 255;
  int gsrc = (g == 0) ? 2 : ((g == 1) ? 0 : 1);
  const float* src = (m == 0) ? wih : whh;
  size_t base = ((size_t)(gsrc * 257 + 1 + j)) * 257 + 1 + 2 * i2;
  __half2 p = __halves2half2(__float2half(src[base]), __float2half(src[base + 1]));
  uint32_t u = *reinterpret_cast<uint32_t*>(&p);
  ((m == 0) ? UT2 : WT2)[(size_t)i2 * 768 + col] = u;
}

// ---------------- kernel A: precompute xU[t*64+b][768] = x_row @ U_g[1:,1:]^T -------
__global__ void precompute_xu(const float* __restrict__ x, const uint32_t* __restrict__ UT2,
                              float* __restrict__ xU) {
  __shared__ float xr[8][256];
  const int tid = threadIdx.x;
  const int row0 = blockIdx.x * 8;
#pragma unroll
  for (int r = 0; r < 8; ++r) {
    int row = row0 + r;
    int t = row >> 6, b = row & 63;
    xr[r][tid] = x[((size_t)b * T_ + t) * 256 + tid];
  }
  __syncthreads();
  float acc[8][3];
#pragma unroll
  for (int r = 0; r < 8; ++r)
#pragma unroll
    for (int c = 0; c < 3; ++c) acc[r][c] = 0.f;

  for (int i2 = 0; i2 < 128; ++i2) {
    float2 w0 = __half22float2(*reinterpret_cast<const __half2*>(&UT2[(size_t)i2*768 + tid]));
    float2 w1 = __half22float2(*reinterpret_cast<const __half2*>(&UT2[(size_t)i2*768 + 256 + tid]));
    float2 w2 = __half22float2(*reinterpret_cast<const __half2*>(&UT2[(size_t)i2*768 + 512 + tid]));
#pragma unroll
    for (int r = 0; r < 8; ++r) {
      float xa = xr[r][2*i2], xb = xr[r][2*i2 + 1];
      acc[r][0] += xa * w0.x + xb * w0.y;
      acc[r][1] += xa * w1.x + xb * w1.y;
      acc[r][2] += xa * w2.x + xb * w2.y;
    }
  }
#pragma unroll
  for (int r = 0; r < 8; ++r)
#pragma unroll
    for (int c = 0; c < 3; ++c)
      xU[(size_t)(row0 + r) * 768 + c * 256 + tid] = acc[r][c];
}

// ---------------- kernel C: the sequential scan, one WG per batch row ----------------
__global__ __launch_bounds__(512, 2) void mobius_gru_scan(
    const float* __restrict__ xU, const uint32_t* __restrict__ WT2,
    const float* __restrict__ bias, const float* __restrict__ kin,
    float* __restrict__ out) {
  __shared__ float2 lds_g2[128];     // gh (then lrh), viewed as pairs for GEMV
  __shared__ float  lds_v[768];      // GEMV results [z | r | h]
  __shared__ float  lds_xu[768];     // xU row for this (t, b)
  float* lds_g = (float*)lds_g2;

  const int tid  = threadIdx.x;
  const int lane = tid & 63;
  const int wave = tid >> 6;
  const int b    = blockIdx.x;

  const float kk    = kin[0];
  const float K     = 1.0f / kk;
  const float sqrtK = sqrtf(K);

  // hoisted lm(expmap0(bias_g)): t-invariant. gate order z,r,h -> bias rows 2,0,1
  float lmeb[3][4];
  {
    const int rows[3] = {2, 0, 1};
#pragma unroll
    for (int g = 0; g < 3; ++g) {
      float bs[4];
#pragma unroll
      for (int e = 0; e < 4; ++e) bs[e] = bias[rows[g] * H1_ + 1 + lane + 64 * e];
      float e0, es[4];
      expmap0_(bs, K, sqrtK, e0, es);
      logmap0_(e0, es, sqrtK, lmeb[g]);
    }
  }

  float h0c = 0.f, hs[4] = {0.f, 0.f, 0.f, 0.f};   // h = zeros(257), as reference

  for (int t = 0; t < T_; ++t) {
    float gh[4];
    logmap0_(h0c, hs, sqrtK, gh);
    if (wave == 0) {
#pragma unroll
      for (int e = 0; e < 4; ++e) lds_g[lane + 64 * e] = gh[e];
    }
    __syncthreads();

    // ---- GEMV phase 1: cols [0,512) = z,r gates; also stage xU row ----
    {
      const float* xrow = xU + (size_t)(t * B_ + b) * 768;
      lds_xu[tid] = xrow[tid];
      if (tid < 256) lds_xu[512 + tid] = xrow[512 + tid];
      float acc = 0.f;
#pragma unroll 4
      for (int i2 = 0; i2 < 128; ++i2) {
        __half2 wv = *reinterpret_cast<const __half2*>(&WT2[(size_t)i2 * 768 + tid]);
        float2 wf = __half22float2(wv);
        float2 gg = lds_g2[i2];
        acc += gg.x * wf.x + gg.y * wf.y;
      }
      lds_v[tid] = acc;
    }
    __syncthreads();

    // ---- gates z, r (redundant per wave; no barriers inside) ----
    float zg[4], rg[4];
    {
      float v[4], xv[4];
#pragma unroll
      for (int e = 0; e < 4; ++e) { int i = lane + 64 * e; v[e] = lds_v[i]; xv[e] = lds_xu[i]; }
      float m0, ms[4]; expmap0_(v, K, sqrtK, m0, ms);
      float q0, qs[4]; expmap0_(xv, K, sqrtK, q0, qs);
      float lq[4];     logmap0_(q0, qs, sqrtK, lq);
      madd_(m0, ms, lq, K, sqrtK);
      madd_(m0, ms, lmeb[0], K, sqrtK);
      float p[4]; logmap0_(m0, ms, sqrtK, p);
#pragma unroll
      for (int e = 0; e < 4; ++e) zg[e] = 1.0f / (1.0f + expf(-p[e]));
    }
    {
      float v[4], xv[4];
#pragma unroll
      for (int e = 0; e < 4; ++e) { int i = lane + 64 * e; v[e] = lds_v[256 + i]; xv[e] = lds_xu[256 + i]; }
      float m0, ms[4]; expmap0_(v, K, sqrtK, m0, ms);
      float q0, qs[4]; expmap0_(xv, K, sqrtK, q0, qs);
      float lq[4];     logmap0_(q0, qs, sqrtK, lq);
      madd_(m0, ms, lq, K, sqrtK);
      madd_(m0, ms, lmeb[1], K, sqrtK);
      float p[4]; logmap0_(m0, ms, sqrtK, p);
#pragma unroll
      for (int e = 0; e < 4; ++e) rg[e] = 1.0f / (1.0f + expf(-p[e]));
    }

    // rh_t = expmap0(r * logmap0(hx)); lrh = logmap0(rh_t)
    float rhu[4];
#pragma unroll
    for (int e = 0; e < 4; ++e) rhu[e] = rg[e] * gh[e];
    float r0, rs_[4]; expmap0_(rhu, K, sqrtK, r0, rs_);
    float lrh[4];     logmap0_(r0, rs_, sqrtK, lrh);
    if (wave == 0) {
#pragma unroll
      for (int e = 0; e < 4; ++e) lds_g[lane + 64 * e] = lrh[e];
    }
    __syncthreads();

    // ---- GEMV phase 2: cols [512,768) = h gate, input lrh ----
    if (tid < 256) {
      float acc = 0.f;
#pragma unroll 4
      for (int i2 = 0; i2 < 128; ++i2) {
        __half2 wv = *reinterpret_cast<const __half2*>(&WT2[(size_t)i2 * 768 + 512 + tid]);
        float2 wf = __half22float2(wv);
        float2 gg = lds_g2[i2];
        acc += gg.x * wf.x + gg.y * wf.y;
      }
      lds_v[512 + tid] = acc;
    }
    __syncthreads();

    // ---- h_tilde ----
    float t0, ts[4];
    {
      float v[4], xv[4];
#pragma unroll
      for (int e = 0; e < 4; ++e) { int i = lane + 64 * e; v[e] = lds_v[512 + i]; xv[e] = lds_xu[512 + i]; }
      expmap0_(v, K, sqrtK, t0, ts);
      float q0, qs[4]; expmap0_(xv, K, sqrtK, q0, qs);
      float lq[4];     logmap0_(q0, qs, sqrtK, lq);
      madd_(t0, ts, lq, K, sqrtK);
      madd_(t0, ts, lmeb[2], K, sqrtK);
    }

    // delta_h = mobius_add(proj(-hx), h_tilde)
    float n0, ns[4];
#pragma unroll
    for (int e = 0; e < 4; ++e) ns[e] = -hs[e];
    n0 = sqrtf(fmaxf(K + sq4(ns), 1e-7f));
    float lt[4]; logmap0_(t0, ts, sqrtK, lt);
    madd_(n0, ns, lt, K, sqrtK);

    // h_new = expmap(ptransp0(hx, z*logmap0(delta_h)), hx)
    float ld[4]; logmap0_(n0, ns, sqrtK, ld);
    float uu[4];
#pragma unroll
    for (int e = 0; e < 4; ++e) uu[e] = zg[e] * ld[e];
    madd_(h0c, hs, uu, K, sqrtK);

    if (wave == 0) {
      float* orow = out + (size_t)(t * B_ + b) * H1_;
      if (lane == 0) orow[0] = h0c;
#pragma unroll
      for (int e = 0; e < 4; ++e) orow[1 + lane + 64 * e] = hs[e];
    }
  }

  if (wave == 0) {
    float* hrow = out + (size_t)T_ * B_ * H1_ + (size_t)b * 256;
#pragma unroll
    for (int e = 0; e < 4; ++e) hrow[lane + 64 * e] = hs[e];
  }
}

// ---------------- launch ----------------
extern "C" void kernel_launch(void* const* d_in, const int* in_sizes, int n_in,
                              void* d_out, int out_size, void* d_ws, size_t ws_size,
                              hipStream_t stream) {
  const float* x    = (const float*)d_in[0];
  const float* k    = (const float*)d_in[1];
  const float* wih  = (const float*)d_in[2];
  const float* whh  = (const float*)d_in[3];
  const float* bias = (const float*)d_in[4];
  float* out = (float*)d_out;

  // ws layout: UT2 (128*768 u32) | WT2 (128*768 u32) | xU (32768*768 f32)
  uint32_t* UT2 = (uint32_t*)d_ws;
  uint32_t* WT2 = UT2 + 98304;
  float*    xU  = (float*)(WT2 + 98304);

  pack_weights<<<768, 256, 0, stream>>>(wih, whh, UT2, WT2);
  precompute_xu<<<4096, 256, 0, stream>>>(x, UT2, xU);
  mobius_gru_scan<<<B_, 512, 0, stream>>>(xU, WT2, bias, k, out);
}

// Round 3
// 6079.863 us; speedup vs baseline: 2.8743x; 2.8743x over previous
//
#include <hip/hip_runtime.h>
#include <hip/hip_fp16.h>
#include <stdint.h>

#define B_  64
#define T_  512
#define H1_ 257

typedef _Float16 h2 __attribute__((ext_vector_type(2)));

__device__ __forceinline__ float frcp(float x) { return __builtin_amdgcn_rcpf(x); }
__device__ __forceinline__ float frsq(float x) { return __builtin_amdgcn_rsqf(x); }

__device__ __forceinline__ h2 u2h(uint32_t u) { return __builtin_bit_cast(h2, u); }
__device__ __forceinline__ float fdot2(uint32_t a, uint32_t b, float c) {
  return __builtin_amdgcn_fdot2(u2h(a), u2h(b), c, false);
}
__device__ __forceinline__ uint32_t pkh(float a, float b) {
  __half2 h = __halves2half2(__float2half(a), __float2half(b));
  return __builtin_bit_cast(uint32_t, h);
}

// ---- DPP all-lane (64) sum, result broadcast via readlane (wave-uniform) ----
template <int CTRL>
__device__ __forceinline__ float dpp_add(float v) {
  int t = __builtin_amdgcn_update_dpp(0, __builtin_bit_cast(int, v), CTRL, 0xf, 0xf, true);
  return v + __builtin_bit_cast(float, t);
}
__device__ __forceinline__ float wsum(float v) {
  v = dpp_add<0xB1>(v);    // quad_perm [1,0,3,2]
  v = dpp_add<0x4E>(v);    // quad_perm [2,3,0,1]
  v = dpp_add<0x141>(v);   // row_half_mirror
  v = dpp_add<0x140>(v);   // row_mirror  -> each 16-row uniform = row sum
  int xi = __builtin_bit_cast(int, v);
  float a = __builtin_bit_cast(float, __builtin_amdgcn_readlane(xi, 0));
  float b = __builtin_bit_cast(float, __builtin_amdgcn_readlane(xi, 16));
  float c = __builtin_bit_cast(float, __builtin_amdgcn_readlane(xi, 32));
  float d = __builtin_bit_cast(float, __builtin_amdgcn_readlane(xi, 48));
  return (a + b) + (c + d);
}

__device__ __forceinline__ float sq4(const float* s) {
  return wsum(s[0]*s[0] + s[1]*s[1] + s[2]*s[2] + s[3]*s[3]);
}
__device__ __forceinline__ float dot4(const float* a, const float* b) {
  return wsum(a[0]*b[0] + a[1]*b[1] + a[2]*b[2] + a[3]*b[3]);
}

// logmap0(x)[1:], stable acosh = log(th + sqrt(th^2-1)), ref clip th>=1+1e-7 kept
__device__ __forceinline__ void logmap0_(float x0, const float* s, float sqrtK, float rsqK, float* o) {
  float ss = fmaxf(sq4(s), 1e-30f);
  float yn = sqrtf(ss);
  float th = fmaxf(x0 * rsqK, 1.0f + 1e-7f);
  float ac = __logf(th + sqrtf(th*th - 1.0f));
  float c  = sqrtK * ac * frcp(yn);
#pragma unroll
  for (int e = 0; e < 4; ++e) o[e] = c * s[e];
}

// expmap0 (spatial tangent) fused with proj
__device__ __forceinline__ void expmap0_(const float* u, float K, float sqrtK, float rsqK,
                                         float& x0, float* s) {
  float ss = fmaxf(sq4(u), 1e-30f);
  float sn = sqrtf(ss);
  float th = sn * rsqK;
  float ex = __expf(th), ei = frcp(ex);
  float c  = sqrtK * (0.5f * (ex - ei)) * frcp(sn);
#pragma unroll
  for (int e = 0; e < 4; ++e) s[e] = c * u[e];
  x0 = sqrtf(fmaxf(K + sq4(s), 1e-7f));
}

// X <- proj(expmap(proj_tan(ptransp0-core(X, lm)), X)) — mirrors reference clips
__device__ __forceinline__ void madd_(float& x0, float* xs, const float* lm,
                                      float K, float sqrtK, float rsqK) {
  float ssx = fmaxf(sq4(xs), 1e-30f);
  float inv = frsq(ssx);
  float yh[4];
#pragma unroll
  for (int e = 0; e < 4; ++e) yh[e] = xs[e] * inv;
  float alpha = dot4(yh, lm) * rsqK;
  float c2 = alpha * (sqrtK - x0);
  float w[4];
#pragma unroll
  for (int e = 0; e < 4; ++e) w[e] = lm[e] - c2 * yh[e];
  float ux = dot4(xs, w);
  float w0 = ux * frcp(fmaxf(x0, 1e-7f));
  float md = sq4(w) - w0 * w0;
  float mn = sqrtf(fmaxf(md, 1e-7f));
  float th = fmaxf(fminf(mn, 1e6f) * rsqK, 1e-15f);
  float ex = __expf(th), ei = frcp(ex);
  float ch = 0.5f * (ex + ei);
  float sh = 0.5f * (ex - ei) * frcp(th);
  float rs[4];
#pragma unroll
  for (int e = 0; e < 4; ++e) rs[e] = ch * xs[e] + sh * w[e];
  x0 = sqrtf(fmaxf(K + sq4(rs), 1e-7f));
#pragma unroll
  for (int e = 0; e < 4; ++e) xs[e] = rs[e];
}

// full gate chain: expmap0(v) ⊕ expmap0(xv) ⊕ expmap0(bias); returns sigmoid(logmap0(.))
__device__ __forceinline__ void gate_chain(float4 v4, float4 x4, const float* lmeb_g,
                                           float K, float sqrtK, float rsqK, float* sig) {
  float v[4]  = {v4.x, v4.y, v4.z, v4.w};
  float xv[4] = {x4.x, x4.y, x4.z, x4.w};
  float m0, ms[4]; expmap0_(v, K, sqrtK, rsqK, m0, ms);
  float q0, qs[4]; expmap0_(xv, K, sqrtK, rsqK, q0, qs);
  float lq[4];     logmap0_(q0, qs, sqrtK, rsqK, lq);
  madd_(m0, ms, lq, K, sqrtK, rsqK);
  madd_(m0, ms, lmeb_g, K, sqrtK, rsqK);
  float p[4]; logmap0_(m0, ms, sqrtK, rsqK, p);
#pragma unroll
  for (int e = 0; e < 4; ++e) sig[e] = frcp(1.0f + __expf(-p[e]));
}

// ---------------- pack weights: uint4[k4*768+col] = 4x half2 (8 K-values) ----------
// col in [0,768): gate g = col>>8 (z,r,h -> src rows 2,0,1), hidden j = col&255.
__global__ void pack_weights(const float* __restrict__ wih, const float* __restrict__ whh,
                             uint4* __restrict__ Pih, uint4* __restrict__ Phh) {
  int idx = blockIdx.x * 256 + threadIdx.x;      // 0..49151
  int m   = idx / 24576;
  int rem = idx % 24576;
  int k4  = rem / 768;
  int col = rem % 768;
  int g   = col >> 8;
  int j   = col & 255;
  int gsrc = (g == 0) ? 2 : ((g == 1) ? 0 : 1);
  const float* src = (m == 0) ? wih : whh;
  const float* row = src + (size_t)(gsrc * H1_ + 1 + j) * H1_ + 1 + 8 * k4;
  uint4 o;
  o.x = pkh(row[0], row[1]);
  o.y = pkh(row[2], row[3]);
  o.z = pkh(row[4], row[5]);
  o.w = pkh(row[6], row[7]);
  ((m == 0) ? Pih : Phh)[(size_t)k4 * 768 + col] = o;
}

// ---------------- precompute xU[t*64+b][768] = x_row @ U_g[1:,1:]^T (dot2) ----------
__global__ void precompute_xu(const float* __restrict__ x, const uint4* __restrict__ U4,
                              float* __restrict__ xU) {
  __shared__ __align__(16) uint32_t xp[8][128];
  const int tid = threadIdx.x;
  const int row0 = blockIdx.x * 8;
#pragma unroll
  for (int it = 0; it < 4; ++it) {
    int item = it * 256 + tid;                   // 0..1023
    int r = item >> 7, i = item & 127;
    int row = row0 + r;
    int t = row >> 6, bb = row & 63;
    const float* xr = x + ((size_t)bb * T_ + t) * 256;
    float2 xv = ((const float2*)xr)[i];
    xp[r][i] = pkh(xv.x, xv.y);
  }
  __syncthreads();
  float acc[8][3];
#pragma unroll
  for (int r = 0; r < 8; ++r)
#pragma unroll
    for (int c = 0; c < 3; ++c) acc[r][c] = 0.f;

#pragma unroll 2
  for (int k4 = 0; k4 < 32; ++k4) {
    uint4 w0 = U4[(size_t)k4 * 768 + tid];
    uint4 w1 = U4[(size_t)k4 * 768 + 256 + tid];
    uint4 w2 = U4[(size_t)k4 * 768 + 512 + tid];
#pragma unroll
    for (int r = 0; r < 8; ++r) {
      uint4 gp = ((const uint4*)xp[r])[k4];
      acc[r][0] = fdot2(w0.x, gp.x, acc[r][0]); acc[r][0] = fdot2(w0.y, gp.y, acc[r][0]);
      acc[r][0] = fdot2(w0.z, gp.z, acc[r][0]); acc[r][0] = fdot2(w0.w, gp.w, acc[r][0]);
      acc[r][1] = fdot2(w1.x, gp.x, acc[r][1]); acc[r][1] = fdot2(w1.y, gp.y, acc[r][1]);
      acc[r][1] = fdot2(w1.z, gp.z, acc[r][1]); acc[r][1] = fdot2(w1.w, gp.w, acc[r][1]);
      acc[r][2] = fdot2(w2.x, gp.x, acc[r][2]); acc[r][2] = fdot2(w2.y, gp.y, acc[r][2]);
      acc[r][2] = fdot2(w2.z, gp.z, acc[r][2]); acc[r][2] = fdot2(w2.w, gp.w, acc[r][2]);
    }
  }
#pragma unroll
  for (int r = 0; r < 8; ++r)
#pragma unroll
    for (int c = 0; c < 3; ++c)
      xU[(size_t)(row0 + r) * 768 + c * 256 + tid] = acc[r][c];
}

// ---------------- the sequential scan, one WG per batch row ----------------
// element layout: lane L holds elements [4L, 4L+4) of each 256-vector
__global__ __launch_bounds__(512, 2) void mobius_gru_scan(
    const float* __restrict__ xU, const uint4* __restrict__ W4,
    const float* __restrict__ bias, const float* __restrict__ kin,
    float* __restrict__ out) {
  __shared__ __align__(16) uint32_t lds_gp[128];   // half2-packed g vector (256)
  __shared__ __align__(16) float lds_v[768];       // GEMV results [z | r | h]
  __shared__ __align__(16) float lds_xu[768];      // xU row for (t, b)

  const int tid  = threadIdx.x;
  const int lane = tid & 63;
  const int wave = tid >> 6;
  const int b    = blockIdx.x;

  const float kk    = kin[0];
  const float K     = 1.0f / kk;
  const float sqrtK = sqrtf(K);
  const float rsqK  = 1.0f / sqrtK;

  // hoisted logmap0(expmap0(bias_g)): gate order z,r,h -> bias rows 2,0,1
  float lmeb[3][4];
  {
    const int rows[3] = {2, 0, 1};
#pragma unroll
    for (int g = 0; g < 3; ++g) {
      float bs[4];
#pragma unroll
      for (int e = 0; e < 4; ++e) bs[e] = bias[rows[g] * H1_ + 1 + 4 * lane + e];
      float e0, es[4];
      expmap0_(bs, K, sqrtK, rsqK, e0, es);
      logmap0_(e0, es, sqrtK, rsqK, lmeb[g]);
    }
  }

  float h0c = 0.f, hs[4] = {0.f, 0.f, 0.f, 0.f};

  // prefetch xU row for t=0
  float xa, xb;
  {
    const float* xrow = xU + (size_t)b * 768;    // t=0
    xa = xrow[tid];
    xb = (tid < 256) ? xrow[512 + tid] : 0.f;
  }

  for (int t = 0; t < T_; ++t) {
    float gh[4];
    logmap0_(h0c, hs, sqrtK, rsqK, gh);
    if (wave == 0) {
      uint2 p; p.x = pkh(gh[0], gh[1]); p.y = pkh(gh[2], gh[3]);
      ((uint2*)lds_gp)[lane] = p;
    }
    __syncthreads();   // B1

    // ---- phase 1: stage xU row, GEMV cols [0,512) = z,r ----
    lds_xu[tid] = xa;
    if (tid < 256) lds_xu[512 + tid] = xb;
    {
      float a0 = 0.f, a1 = 0.f, a2 = 0.f, a3 = 0.f;
#pragma unroll 4
      for (int k4 = 0; k4 < 32; ++k4) {
        uint4 w  = W4[(size_t)k4 * 768 + tid];
        uint4 gp = ((const uint4*)lds_gp)[k4];
        a0 = fdot2(w.x, gp.x, a0);
        a1 = fdot2(w.y, gp.y, a1);
        a2 = fdot2(w.z, gp.z, a2);
        a3 = fdot2(w.w, gp.w, a3);
      }
      lds_v[tid] = (a0 + a1) + (a2 + a3);
    }
    // prefetch next step's xU row (hidden under the rest of this step)
    if (t + 1 < T_) {
      const float* nx = xU + (size_t)((t + 1) * B_ + b) * 768;
      xa = nx[tid];
      xb = (tid < 256) ? nx[512 + tid] : 0.f;
    }
    __syncthreads();   // B2

    // ---- gates z, r (redundant per wave; pure VALU/DPP, no barriers) ----
    float zg[4], rg[4];
    gate_chain(((const float4*)lds_v)[lane],       ((const float4*)lds_xu)[lane],
               lmeb[0], K, sqrtK, rsqK, zg);
    gate_chain(((const float4*)lds_v)[64 + lane],  ((const float4*)lds_xu)[64 + lane],
               lmeb[1], K, sqrtK, rsqK, rg);

    // rh_t = expmap0(r * logmap0(hx)); lrh = logmap0(rh_t)
    float rhu[4];
#pragma unroll
    for (int e = 0; e < 4; ++e) rhu[e] = rg[e] * gh[e];
    float r0, rs_[4]; expmap0_(rhu, K, sqrtK, rsqK, r0, rs_);
    float lrh[4];     logmap0_(r0, rs_, sqrtK, rsqK, lrh);
    if (wave == 0) {
      uint2 p; p.x = pkh(lrh[0], lrh[1]); p.y = pkh(lrh[2], lrh[3]);
      ((uint2*)lds_gp)[lane] = p;
    }
    __syncthreads();   // B3

    // ---- phase 2: GEMV cols [512,768) = h gate ----
    if (tid < 256) {
      float a0 = 0.f, a1 = 0.f, a2 = 0.f, a3 = 0.f;
#pragma unroll 4
      for (int k4 = 0; k4 < 32; ++k4) {
        uint4 w  = W4[(size_t)k4 * 768 + 512 + tid];
        uint4 gp = ((const uint4*)lds_gp)[k4];
        a0 = fdot2(w.x, gp.x, a0);
        a1 = fdot2(w.y, gp.y, a1);
        a2 = fdot2(w.z, gp.z, a2);
        a3 = fdot2(w.w, gp.w, a3);
      }
      lds_v[512 + tid] = (a0 + a1) + (a2 + a3);
    }
    __syncthreads();   // B4

    // ---- h_tilde ----
    float t0, ts[4];
    {
      float4 v4 = ((const float4*)lds_v)[128 + lane];
      float4 x4 = ((const float4*)lds_xu)[128 + lane];
      float v[4]  = {v4.x, v4.y, v4.z, v4.w};
      float xv[4] = {x4.x, x4.y, x4.z, x4.w};
      expmap0_(v, K, sqrtK, rsqK, t0, ts);
      float q0, qs[4]; expmap0_(xv, K, sqrtK, rsqK, q0, qs);
      float lq[4];     logmap0_(q0, qs, sqrtK, rsqK, lq);
      madd_(t0, ts, lq, K, sqrtK, rsqK);
      madd_(t0, ts, lmeb[2], K, sqrtK, rsqK);
    }

    // delta_h = mobius_add(proj(-hx), h_tilde)
    float n0, ns[4];
#pragma unroll
    for (int e = 0; e < 4; ++e) ns[e] = -hs[e];
    n0 = sqrtf(fmaxf(K + sq4(ns), 1e-7f));
    float lt[4]; logmap0_(t0, ts, sqrtK, rsqK, lt);
    madd_(n0, ns, lt, K, sqrtK, rsqK);

    // h_new = expmap(ptransp0(hx, z*logmap0(delta_h)), hx)
    float ld[4]; logmap0_(n0, ns, sqrtK, rsqK, ld);
    float uu[4];
#pragma unroll
    for (int e = 0; e < 4; ++e) uu[e] = zg[e] * ld[e];
    madd_(h0c, hs, uu, K, sqrtK, rsqK);

    if (wave == 0) {
      float* orow = out + (size_t)(t * B_ + b) * H1_;
      if (lane == 0) orow[0] = h0c;
#pragma unroll
      for (int e = 0; e < 4; ++e) orow[1 + 4 * lane + e] = hs[e];
    }
  }

  if (wave == 0) {
    float4 hv = {hs[0], hs[1], hs[2], hs[3]};
    ((float4*)(out + (size_t)T_ * B_ * H1_ + (size_t)b * 256))[lane] = hv;
  }
}

// ---------------- launch ----------------
extern "C" void kernel_launch(void* const* d_in, const int* in_sizes, int n_in,
                              void* d_out, int out_size, void* d_ws, size_t ws_size,
                              hipStream_t stream) {
  const float* x    = (const float*)d_in[0];
  const float* k    = (const float*)d_in[1];
  const float* wih  = (const float*)d_in[2];
  const float* whh  = (const float*)d_in[3];
  const float* bias = (const float*)d_in[4];
  float* out = (float*)d_out;

  // ws layout: Pih (24576 uint4) | Phh (24576 uint4) | xU (32768*768 f32)
  uint4* Pih = (uint4*)d_ws;
  uint4* Phh = Pih + 24576;
  float* xU  = (float*)(Phh + 24576);

  pack_weights<<<192, 256, 0, stream>>>(wih, whh, Pih, Phh);
  precompute_xu<<<4096, 256, 0, stream>>>(x, Pih, xU);
  mobius_gru_scan<<<B_, 512, 0, stream>>>(xU, Phh, bias, k, out);
}

// Round 5
// 3663.027 us; speedup vs baseline: 4.7707x; 1.6598x over previous
//
#include <hip/hip_runtime.h>
#include <hip/hip_fp16.h>
#include <stdint.h>

#define B_  64
#define T_  512
#define H1_ 257

typedef _Float16 h2v __attribute__((ext_vector_type(2)));

__device__ __forceinline__ float frcp(float x) { return __builtin_amdgcn_rcpf(x); }
__device__ __forceinline__ float frsq(float x) { return __builtin_amdgcn_rsqf(x); }
__device__ __forceinline__ h2v u2h(uint32_t u) { return __builtin_bit_cast(h2v, u); }
__device__ __forceinline__ float fdot2(uint32_t a, uint32_t b, float c) {
  return __builtin_amdgcn_fdot2(u2h(a), u2h(b), c, false);
}
__device__ __forceinline__ uint32_t pkh(float a, float b) {
  __half2 h = __halves2half2(__float2half(a), __float2half(b));
  return __builtin_bit_cast(uint32_t, h);
}

// ---- DPP wave64 sum, broadcast via readlane ----
template <int CTRL>
__device__ __forceinline__ float dpp_add(float v) {
  int t = __builtin_amdgcn_update_dpp(0, __builtin_bit_cast(int, v), CTRL, 0xf, 0xf, true);
  return v + __builtin_bit_cast(float, t);
}
__device__ __forceinline__ float wsum(float v) {
  v = dpp_add<0xB1>(v);    // quad_perm [1,0,3,2]
  v = dpp_add<0x4E>(v);    // quad_perm [2,3,0,1]
  v = dpp_add<0x141>(v);   // row_half_mirror
  v = dpp_add<0x140>(v);   // row_mirror -> 16-lane-row sums
  int xi = __builtin_bit_cast(int, v);
  float a = __builtin_bit_cast(float, __builtin_amdgcn_readlane(xi, 0));
  float b = __builtin_bit_cast(float, __builtin_amdgcn_readlane(xi, 16));
  float c = __builtin_bit_cast(float, __builtin_amdgcn_readlane(xi, 32));
  float d = __builtin_bit_cast(float, __builtin_amdgcn_readlane(xi, 48));
  return (a + b) + (c + d);
}
__device__ __forceinline__ float sq4w(const float* s) {
  return wsum(s[0]*s[0] + s[1]*s[1] + s[2]*s[2] + s[3]*s[3]);
}
__device__ __forceinline__ float dot4w(const float* a, const float* b) {
  return wsum(a[0]*b[0] + a[1]*b[1] + a[2]*b[2] + a[3]*b[3]);
}

// logmap0 spatial: o = c*s. ss must be TRUE |s|^2 (consistency-critical: frcp(yn)).
__device__ __forceinline__ float logc_(float x0, float ss, float sqrtK, float rsqK) {
  float yn = sqrtf(fmaxf(ss, 1e-30f));
  float th = fmaxf(x0 * rsqK, 1.0f + 1e-7f);
  float ac = __logf(th + sqrtf(th*th - 1.0f));
  return sqrtK * ac * frcp(yn);
}
__device__ __forceinline__ void logmap0o_(float x0, const float* s, float ss,
                                          float sqrtK, float rsqK, float* o) {
  float c = logc_(x0, ss, sqrtK, rsqK);
#pragma unroll
  for (int e = 0; e < 4; ++e) o[e] = c * s[e];
}
__device__ __forceinline__ void logmap0c_(float x0, const float* s, float ss,
                                          float K, float sqrtK, float rsqK,
                                          float* o, float& sso) {
  float yn = sqrtf(fmaxf(ss, 1e-30f));
  float th = fmaxf(x0 * rsqK, 1.0f + 1e-7f);
  float ac = __logf(th + sqrtf(th*th - 1.0f));
  float c  = sqrtK * ac * frcp(yn);
#pragma unroll
  for (int e = 0; e < 4; ++e) o[e] = c * s[e];
  sso = K * ac * ac;   // exact given true input ss
}

// expmap0+proj, in-place u->s; single multiplicative scale => ss_s safe algebraic
__device__ __forceinline__ void expmap0c_(float* u, float ss_u, float K, float sqrtK,
                                          float rsqK, float& x0, float& ss_s) {
  float sn = sqrtf(fmaxf(ss_u, 1e-30f));
  float th = sn * rsqK;
  float ex = __expf(th), ei = frcp(ex);
  float sh = 0.5f * (ex - ei);
  float c  = sqrtK * sh * frcp(sn);
#pragma unroll
  for (int e = 0; e < 4; ++e) u[e] = c * u[e];
  float t = sqrtK * sh;
  ss_s = t * t;
  x0 = sqrtf(fmaxf(K + ss_s, 1e-7f));
}

// full mobius-add core: X <- proj(expmap(proj_tan(ptransp0(X,lm)),X)). 2 wsums.
// Final ss RECOMPUTED exactly (cancellation in |ch*xs+sh*w|^2 breaks algebraic carry).
__device__ __forceinline__ void maddc_(float& x0, float* xs, float& ss,
                                       const float* lm, float ssl,
                                       float K, float sqrtK, float rsqK) {
  float inv = frsq(fmaxf(ss, 1e-30f));
  float dotXL = dot4w(xs, lm);
  float alpha = inv * dotXL * rsqK;
  float c2 = alpha * (sqrtK - x0);
  float ciw = c2 * inv;
  float w[4];
#pragma unroll
  for (int e = 0; e < 4; ++e) w[e] = lm[e] - ciw * xs[e];
  float ux = dotXL - ciw * ss;
  float w0 = ux * frcp(fmaxf(x0, 1e-7f));
  float ssw = fmaxf(ssl - 2.0f*ciw*dotXL + ciw*ciw*ss, 0.0f);
  float md = ssw - w0 * w0;
  float mn = sqrtf(fmaxf(md, 1e-7f));
  float th = fmaxf(fminf(mn, 1e6f) * rsqK, 1e-15f);
  float ex = __expf(th), ei = frcp(ex);
  float ch = 0.5f * (ex + ei);
  float sh = 0.5f * (ex - ei) * frcp(th);
#pragma unroll
  for (int e = 0; e < 4; ++e) xs[e] = ch * xs[e] + sh * w[e];
  ss = sq4w(xs);                       // TRUE norm^2 — the R4 NaN fix
  x0 = sqrtf(fmaxf(K + ss, 1e-7f));
}

// small-theta mobius-add (bias, |lm|~1e-4): cosh~1, sinh(t)/t~1; relative
// perturbation of ss is ~1e-4 => algebraic carry safe (no cancellation).
__device__ __forceinline__ void madds_(float& x0, float* xs, float& ss,
                                       const float* lm, float ssl,
                                       float K, float sqrtK, float rsqK) {
  float inv = frsq(fmaxf(ss, 1e-30f));
  float dotXL = dot4w(xs, lm);
  float alpha = inv * dotXL * rsqK;
  float c2 = alpha * (sqrtK - x0);
  float ciw = c2 * inv;
  float ux = dotXL - ciw * ss;
  float ssw = fmaxf(ssl - 2.0f*ciw*dotXL + ciw*ciw*ss, 0.0f);
  float nss = ss + 2.0f*ux + ssw;
#pragma unroll
  for (int e = 0; e < 4; ++e) xs[e] += lm[e] - ciw * xs[e];
  ss = fmaxf(nss, 0.0f);
  x0 = sqrtf(fmaxf(K + ss, 1e-7f));
}

// gate: v (GEMV out), lq (=xU), bias lm; -> sigmoid(logmap0(chain))
__device__ __forceinline__ void gate_chain(float* v, const float* lq, float ssl_q,
                                           const float* lmb, float ssl_b,
                                           float K, float sqrtK, float rsqK, float* sig) {
  float ssv = sq4w(v);
  float m0, ssm;
  expmap0c_(v, ssv, K, sqrtK, rsqK, m0, ssm);
  maddc_(m0, v, ssm, lq, ssl_q, K, sqrtK, rsqK);
  madds_(m0, v, ssm, lmb, ssl_b, K, sqrtK, rsqK);
  float c = logc_(m0, ssm, sqrtK, rsqK);
#pragma unroll
  for (int e = 0; e < 4; ++e) sig[e] = frcp(1.0f + __expf(-c * v[e]));
}

// ---------------- pack weights: uint4[k4*768+col] = 4x half2 ----------------
__global__ void pack_weights(const float* __restrict__ wih, const float* __restrict__ whh,
                             uint4* __restrict__ Pih, uint4* __restrict__ Phh) {
  int idx = blockIdx.x * 256 + threadIdx.x;
  int m   = idx / 24576;
  int rem = idx % 24576;
  int k4  = rem / 768;
  int col = rem % 768;
  int g   = col >> 8;
  int j   = col & 255;
  int gsrc = (g == 0) ? 2 : ((g == 1) ? 0 : 1);
  const float* src = (m == 0) ? wih : whh;
  const float* row = src + (size_t)(gsrc * H1_ + 1 + j) * H1_ + 1 + 8 * k4;
  uint4 o;
  o.x = pkh(row[0], row[1]);
  o.y = pkh(row[2], row[3]);
  o.z = pkh(row[4], row[5]);
  o.w = pkh(row[6], row[7]);
  ((m == 0) ? Pih : Phh)[(size_t)k4 * 768 + col] = o;
}

// ---------------- precompute xU[t*64+b][768] = x_row @ U^T ----------------
__global__ void precompute_xu(const float* __restrict__ x, const uint4* __restrict__ U4,
                              float* __restrict__ xU) {
  __shared__ __align__(16) uint32_t xp[8][128];
  const int tid = threadIdx.x;
  const int row0 = blockIdx.x * 8;
#pragma unroll
  for (int it = 0; it < 4; ++it) {
    int item = it * 256 + tid;
    int r = item >> 7, i = item & 127;
    int row = row0 + r;
    int t = row >> 6, bb = row & 63;
    const float* xr = x + ((size_t)bb * T_ + t) * 256;
    float2 xv = ((const float2*)xr)[i];
    xp[r][i] = pkh(xv.x, xv.y);
  }
  __syncthreads();
  float acc[8][3];
#pragma unroll
  for (int r = 0; r < 8; ++r)
#pragma unroll
    for (int c = 0; c < 3; ++c) acc[r][c] = 0.f;

#pragma unroll 2
  for (int k4 = 0; k4 < 32; ++k4) {
    uint4 w0 = U4[(size_t)k4 * 768 + tid];
    uint4 w1 = U4[(size_t)k4 * 768 + 256 + tid];
    uint4 w2 = U4[(size_t)k4 * 768 + 512 + tid];
#pragma unroll
    for (int r = 0; r < 8; ++r) {
      uint4 gp = ((const uint4*)xp[r])[k4];
      acc[r][0] = fdot2(w0.x, gp.x, acc[r][0]); acc[r][0] = fdot2(w0.y, gp.y, acc[r][0]);
      acc[r][0] = fdot2(w0.z, gp.z, acc[r][0]); acc[r][0] = fdot2(w0.w, gp.w, acc[r][0]);
      acc[r][1] = fdot2(w1.x, gp.x, acc[r][1]); acc[r][1] = fdot2(w1.y, gp.y, acc[r][1]);
      acc[r][1] = fdot2(w1.z, gp.z, acc[r][1]); acc[r][1] = fdot2(w1.w, gp.w, acc[r][1]);
      acc[r][2] = fdot2(w2.x, gp.x, acc[r][2]); acc[r][2] = fdot2(w2.y, gp.y, acc[r][2]);
      acc[r][2] = fdot2(w2.z, gp.z, acc[r][2]); acc[r][2] = fdot2(w2.w, gp.w, acc[r][2]);
    }
  }
#pragma unroll
  for (int r = 0; r < 8; ++r)
#pragma unroll
    for (int c = 0; c < 3; ++c)
      xU[(size_t)(row0 + r) * 768 + c * 256 + tid] = acc[r][c];
}

// ---------------- xUss[row*3+g] = |xU_row_gate|^2 ----------------
__global__ void xuss_kernel(const float* __restrict__ xU, float* __restrict__ xUss) {
  int row  = (blockIdx.x * 256 + threadIdx.x) >> 6;
  int lane = threadIdx.x & 63;
  const float4* base = (const float4*)(xU + (size_t)row * 768);
#pragma unroll
  for (int g = 0; g < 3; ++g) {
    float4 v = base[g * 64 + lane];
    float s = wsum(v.x*v.x + v.y*v.y + v.z*v.z + v.w*v.w);
    if (lane == 0) xUss[(size_t)row * 3 + g] = s;
  }
}

// ---------------- sequential scan, one WG per batch row ----------------
__global__ __launch_bounds__(512, 2) void mobius_gru_scan(
    const float* __restrict__ xU, const float* __restrict__ xUss,
    const uint4* __restrict__ W4, const float* __restrict__ bias,
    const float* __restrict__ kin, float* __restrict__ out) {
  __shared__ __align__(16) uint32_t lds_gp[128];   // packed g vector (256 halves)
  __shared__ __align__(16) float lds_v[512];       // GEMV1 results [z | r]
  __shared__ __align__(16) float lds_v2[512];      // GEMV2 split-K partials
  __shared__ __align__(16) float lds_xu[768];      // lq rows [z | r | h]
  __shared__ __align__(16) float lds_zg[256];      // z gate

  const int tid  = threadIdx.x;
  const int lane = tid & 63;
  const int wave = tid >> 6;
  const int b    = blockIdx.x;

  const float kk    = kin[0];
  const float K     = 1.0f / kk;
  const float sqrtK = sqrtf(K);
  const float rsqK  = 1.0f / sqrtK;

  // bias tangent = spatial part directly (logmap0(expmap0(b)) == b); |b|^2 per gate
  float lmeb[3][4]; float sslb[3];
  {
    const int rows[3] = {2, 0, 1};   // z, r, h
#pragma unroll
    for (int g = 0; g < 3; ++g) {
#pragma unroll
      for (int e = 0; e < 4; ++e) lmeb[g][e] = bias[rows[g] * H1_ + 1 + 4 * lane + e];
      sslb[g] = sq4w(lmeb[g]);
    }
  }

  float h0c = 0.f, hs[4] = {0.f, 0.f, 0.f, 0.f}, ssh = 0.f;

  // prefetch t=0 lq row + norms
  float xa, xb, nsv0, nsv1, nsv2;
  {
    const float* xrow = xU + (size_t)b * 768;
    xa = xrow[tid];
    xb = (tid < 256) ? xrow[512 + tid] : 0.f;
    const float* srow = xUss + (size_t)b * 3;
    nsv0 = srow[0]; nsv1 = srow[1]; nsv2 = srow[2];
  }

  for (int t = 0; t < T_; ++t) {
    const float s0 = nsv0, s1 = nsv1, s2 = nsv2;   // current-step |lq_g|^2

    // gh = logmap0(h): ssh is true (recomputed in final maddc_ of prev step)
    float gh[4];
    logmap0o_(h0c, hs, ssh, sqrtK, rsqK, gh);
    if (wave == 0) {
      uint2 p; p.x = pkh(gh[0], gh[1]); p.y = pkh(gh[2], gh[3]);
      ((uint2*)lds_gp)[lane] = p;
    }
    __syncthreads();   // B1

    // ---- phase 1: stage lq row, GEMV1 cols [0,512) = z,r ----
    lds_xu[tid] = xa;
    if (tid < 256) lds_xu[512 + tid] = xb;
    {
      float a0 = 0.f, a1 = 0.f, a2 = 0.f, a3 = 0.f;
#pragma unroll 4
      for (int k4 = 0; k4 < 32; ++k4) {
        uint4 w  = W4[(size_t)k4 * 768 + tid];
        uint4 gp = ((const uint4*)lds_gp)[k4];
        a0 = fdot2(w.x, gp.x, a0);
        a1 = fdot2(w.y, gp.y, a1);
        a2 = fdot2(w.z, gp.z, a2);
        a3 = fdot2(w.w, gp.w, a3);
      }
      lds_v[tid] = (a0 + a1) + (a2 + a3);
    }
    if (t + 1 < T_) {   // prefetch next step
      const float* nx = xU + (size_t)((t + 1) * B_ + b) * 768;
      xa = nx[tid];
      xb = (tid < 256) ? nx[512 + tid] : 0.f;
      const float* srow = xUss + (size_t)((t + 1) * B_ + b) * 3;
      nsv0 = srow[0]; nsv1 = srow[1]; nsv2 = srow[2];
    }
    __syncthreads();   // B2

    if (wave < 4) {
      // ---- r-gate chain + rh_t (critical path) ----
      float v[4], xv[4];
      { float4 t4 = ((const float4*)lds_v)[64 + lane];  v[0]=t4.x; v[1]=t4.y; v[2]=t4.z; v[3]=t4.w; }
      { float4 t4 = ((const float4*)lds_xu)[64 + lane]; xv[0]=t4.x; xv[1]=t4.y; xv[2]=t4.z; xv[3]=t4.w; }
      float rg[4];
      gate_chain(v, xv, s1, lmeb[1], sslb[1], K, sqrtK, rsqK, rg);
      float rhu[4];
#pragma unroll
      for (int e = 0; e < 4; ++e) rhu[e] = rg[e] * gh[e];
      float ssrh = sq4w(rhu);
      float r0, ssr;
      expmap0c_(rhu, ssrh, K, sqrtK, rsqK, r0, ssr);
      float lrh[4];
      logmap0o_(r0, rhu, ssr, sqrtK, rsqK, lrh);
      if (wave == 0) {
        uint2 p; p.x = pkh(lrh[0], lrh[1]); p.y = pkh(lrh[2], lrh[3]);
        ((uint2*)lds_gp)[lane] = p;
      }
    } else {
      // ---- z-gate chain (off critical path) ----
      float v[4], xv[4];
      { float4 t4 = ((const float4*)lds_v)[lane];  v[0]=t4.x; v[1]=t4.y; v[2]=t4.z; v[3]=t4.w; }
      { float4 t4 = ((const float4*)lds_xu)[lane]; xv[0]=t4.x; xv[1]=t4.y; xv[2]=t4.z; xv[3]=t4.w; }
      float zg[4];
      gate_chain(v, xv, s0, lmeb[0], sslb[0], K, sqrtK, rsqK, zg);
      if (wave == 4) {
        float4 z4 = {zg[0], zg[1], zg[2], zg[3]};
        ((float4*)lds_zg)[lane] = z4;
      }
    }
    __syncthreads();   // B3

    // ---- phase 2: GEMV2 cols h, split-K over 512 threads ----
    {
      int j  = tid & 255;
      int kh = tid >> 8;
      float a0 = 0.f, a1 = 0.f, a2 = 0.f, a3 = 0.f;
#pragma unroll 4
      for (int k4 = kh * 16; k4 < kh * 16 + 16; ++k4) {
        uint4 w  = W4[(size_t)k4 * 768 + 512 + j];
        uint4 gp = ((const uint4*)lds_gp)[k4];
        a0 = fdot2(w.x, gp.x, a0);
        a1 = fdot2(w.y, gp.y, a1);
        a2 = fdot2(w.z, gp.z, a2);
        a3 = fdot2(w.w, gp.w, a3);
      }
      lds_v2[kh * 256 + j] = (a0 + a1) + (a2 + a3);
    }
    __syncthreads();   // B4

    // ---- h_tilde chain (all waves redundant) ----
    float t0, ts[4], sst;
    {
      float4 pa = ((const float4*)lds_v2)[lane];
      float4 pb = ((const float4*)lds_v2)[64 + lane];
      ts[0] = pa.x + pb.x; ts[1] = pa.y + pb.y; ts[2] = pa.z + pb.z; ts[3] = pa.w + pb.w;
      float xv[4];
      { float4 t4 = ((const float4*)lds_xu)[128 + lane]; xv[0]=t4.x; xv[1]=t4.y; xv[2]=t4.z; xv[3]=t4.w; }
      float ssv = sq4w(ts);
      expmap0c_(ts, ssv, K, sqrtK, rsqK, t0, sst);
      maddc_(t0, ts, sst, xv, s2, K, sqrtK, rsqK);
      madds_(t0, ts, sst, lmeb[2], sslb[2], K, sqrtK, rsqK);
    }

    // ---- delta_h = mobius_add(proj(-hx), h_tilde) ----
    float n0, ns[4], ssn = ssh;
#pragma unroll
    for (int e = 0; e < 4; ++e) ns[e] = -hs[e];
    n0 = sqrtf(fmaxf(K + ssh, 1e-7f));
    float lt[4], sslt;
    logmap0c_(t0, ts, sst, K, sqrtK, rsqK, lt, sslt);
    maddc_(n0, ns, ssn, lt, sslt, K, sqrtK, rsqK);

    // ---- h_new = expmap(ptransp0(hx, z*logmap0(delta_h)), hx) ----
    float ld[4];
    logmap0o_(n0, ns, ssn, sqrtK, rsqK, ld);
    float uu[4];
    {
      float4 z4 = ((const float4*)lds_zg)[lane];
      uu[0] = z4.x * ld[0]; uu[1] = z4.y * ld[1]; uu[2] = z4.z * ld[2]; uu[3] = z4.w * ld[3];
    }
    float ssuu = sq4w(uu);
    maddc_(h0c, hs, ssh, uu, ssuu, K, sqrtK, rsqK);

    if (wave == 0) {
      float* orow = out + (size_t)(t * B_ + b) * H1_;
      if (lane == 0) orow[0] = h0c;
#pragma unroll
      for (int e = 0; e < 4; ++e) orow[1 + 4 * lane + e] = hs[e];
    }
  }

  if (wave == 0) {
    float4 hv = {hs[0], hs[1], hs[2], hs[3]};
    ((float4*)(out + (size_t)T_ * B_ * H1_ + (size_t)b * 256))[lane] = hv;
  }
}

// ---------------- launch ----------------
extern "C" void kernel_launch(void* const* d_in, const int* in_sizes, int n_in,
                              void* d_out, int out_size, void* d_ws, size_t ws_size,
                              hipStream_t stream) {
  const float* x    = (const float*)d_in[0];
  const float* k    = (const float*)d_in[1];
  const float* wih  = (const float*)d_in[2];
  const float* whh  = (const float*)d_in[3];
  const float* bias = (const float*)d_in[4];
  float* out = (float*)d_out;

  // ws: Pih (24576 uint4, later overlaid by xUss) | Phh (24576 uint4) | xU (32768*768 f)
  uint4* Pih = (uint4*)d_ws;
  uint4* Phh = Pih + 24576;
  float* xU  = (float*)(Phh + 24576);
  float* xUss = (float*)Pih;   // Pih dead after precompute_xu

  pack_weights<<<192, 256, 0, stream>>>(wih, whh, Pih, Phh);
  precompute_xu<<<4096, 256, 0, stream>>>(x, Pih, xU);
  xuss_kernel<<<8192, 256, 0, stream>>>(xU, xUss);
  mobius_gru_scan<<<B_, 512, 0, stream>>>(xU, xUss, Phh, bias, k, out);
}

// Round 6
// 3157.137 us; speedup vs baseline: 5.5352x; 1.1602x over previous
//
#include <hip/hip_runtime.h>
#include <hip/hip_fp16.h>
#include <stdint.h>

#define B_  64
#define T_  512
#define H1_ 257

typedef _Float16 h2v __attribute__((ext_vector_type(2)));

__device__ __forceinline__ float frcp(float x) { return __builtin_amdgcn_rcpf(x); }
__device__ __forceinline__ float frsq(float x) { return __builtin_amdgcn_rsqf(x); }
__device__ __forceinline__ h2v u2h(uint32_t u) { return __builtin_bit_cast(h2v, u); }
__device__ __forceinline__ float fdot2(uint32_t a, uint32_t b, float c) {
  return __builtin_amdgcn_fdot2(u2h(a), u2h(b), c, false);
}
__device__ __forceinline__ uint32_t pkh(float a, float b) {
  __half2 h = __halves2half2(__float2half(a), __float2half(b));
  return __builtin_bit_cast(uint32_t, h);
}

// ---- DPP wave64 sum, broadcast via readlane ----
template <int CTRL>
__device__ __forceinline__ float dpp_add(float v) {
  int t = __builtin_amdgcn_update_dpp(0, __builtin_bit_cast(int, v), CTRL, 0xf, 0xf, true);
  return v + __builtin_bit_cast(float, t);
}
__device__ __forceinline__ float wsum(float v) {
  v = dpp_add<0xB1>(v);    // quad_perm [1,0,3,2]
  v = dpp_add<0x4E>(v);    // quad_perm [2,3,0,1]
  v = dpp_add<0x141>(v);   // row_half_mirror
  v = dpp_add<0x140>(v);   // row_mirror -> 16-lane-row sums
  int xi = __builtin_bit_cast(int, v);
  float a = __builtin_bit_cast(float, __builtin_amdgcn_readlane(xi, 0));
  float b = __builtin_bit_cast(float, __builtin_amdgcn_readlane(xi, 16));
  float c = __builtin_bit_cast(float, __builtin_amdgcn_readlane(xi, 32));
  float d = __builtin_bit_cast(float, __builtin_amdgcn_readlane(xi, 48));
  return (a + b) + (c + d);
}
__device__ __forceinline__ float sq4w(const float* s) {
  return wsum(s[0]*s[0] + s[1]*s[1] + s[2]*s[2] + s[3]*s[3]);
}
__device__ __forceinline__ float dot4w(const float* a, const float* b) {
  return wsum(a[0]*b[0] + a[1]*b[1] + a[2]*b[2] + a[3]*b[3]);
}

// logmap0 spatial: o = c*s. ss must be TRUE |s|^2.
__device__ __forceinline__ float logc_(float x0, float ss, float sqrtK, float rsqK) {
  float yn = sqrtf(fmaxf(ss, 1e-30f));
  float th = fmaxf(x0 * rsqK, 1.0f + 1e-7f);
  float ac = __logf(th + sqrtf(th*th - 1.0f));
  return sqrtK * ac * frcp(yn);
}
__device__ __forceinline__ void logmap0o_(float x0, const float* s, float ss,
                                          float sqrtK, float rsqK, float* o) {
  float c = logc_(x0, ss, sqrtK, rsqK);
#pragma unroll
  for (int e = 0; e < 4; ++e) o[e] = c * s[e];
}
__device__ __forceinline__ void logmap0c_(float x0, const float* s, float ss,
                                          float K, float sqrtK, float rsqK,
                                          float* o, float& sso) {
  float yn = sqrtf(fmaxf(ss, 1e-30f));
  float th = fmaxf(x0 * rsqK, 1.0f + 1e-7f);
  float ac = __logf(th + sqrtf(th*th - 1.0f));
  float c  = sqrtK * ac * frcp(yn);
#pragma unroll
  for (int e = 0; e < 4; ++e) o[e] = c * s[e];
  sso = K * ac * ac;
}

// expmap0+proj, in-place u->s; single scale => ss_s safe algebraic
__device__ __forceinline__ void expmap0c_(float* u, float ss_u, float K, float sqrtK,
                                          float rsqK, float& x0, float& ss_s) {
  float sn = sqrtf(fmaxf(ss_u, 1e-30f));
  float th = sn * rsqK;
  float ex = __expf(th), ei = frcp(ex);
  float sh = 0.5f * (ex - ei);
  float c  = sqrtK * sh * frcp(sn);
#pragma unroll
  for (int e = 0; e < 4; ++e) u[e] = c * u[e];
  float t = sqrtK * sh;
  ss_s = t * t;
  x0 = sqrtf(fmaxf(K + ss_s, 1e-7f));
}

// mobius-add core: X <- proj(expmap(proj_tan(ptransp0(X,lm)),X)). 2 wsums.
__device__ __forceinline__ void maddc_(float& x0, float* xs, float& ss,
                                       const float* lm, float ssl,
                                       float K, float sqrtK, float rsqK) {
  float inv = frsq(fmaxf(ss, 1e-30f));
  float dotXL = dot4w(xs, lm);
  float alpha = inv * dotXL * rsqK;
  float c2 = alpha * (sqrtK - x0);
  float ciw = c2 * inv;
  float w[4];
#pragma unroll
  for (int e = 0; e < 4; ++e) w[e] = lm[e] - ciw * xs[e];
  float ux = dotXL - ciw * ss;
  float w0 = ux * frcp(fmaxf(x0, 1e-7f));
  float ssw = fmaxf(ssl - 2.0f*ciw*dotXL + ciw*ciw*ss, 0.0f);
  float md = ssw - w0 * w0;
  float mn = sqrtf(fmaxf(md, 1e-7f));
  float th = fmaxf(fminf(mn, 1e6f) * rsqK, 1e-15f);
  float ex = __expf(th), ei = frcp(ex);
  float ch = 0.5f * (ex + ei);
  float sh = 0.5f * (ex - ei) * frcp(th);
#pragma unroll
  for (int e = 0; e < 4; ++e) xs[e] = ch * xs[e] + sh * w[e];
  ss = sq4w(xs);                       // TRUE norm^2 (R5 NaN fix)
  x0 = sqrtf(fmaxf(K + ss, 1e-7f));
}

// small-theta mobius-add (bias): no cancellation, algebraic ss carry safe
__device__ __forceinline__ void madds_(float& x0, float* xs, float& ss,
                                       const float* lm, float ssl,
                                       float K, float sqrtK, float rsqK) {
  float inv = frsq(fmaxf(ss, 1e-30f));
  float dotXL = dot4w(xs, lm);
  float alpha = inv * dotXL * rsqK;
  float c2 = alpha * (sqrtK - x0);
  float ciw = c2 * inv;
  float ux = dotXL - ciw * ss;
  float ssw = fmaxf(ssl - 2.0f*ciw*dotXL + ciw*ciw*ss, 0.0f);
  float nss = ss + 2.0f*ux + ssw;
#pragma unroll
  for (int e = 0; e < 4; ++e) xs[e] += lm[e] - ciw * xs[e];
  ss = fmaxf(nss, 0.0f);
  x0 = sqrtf(fmaxf(K + ss, 1e-7f));
}

// gate: v (GEMV out), lq (=xU), bias lm; -> sigmoid(logmap0(chain))
__device__ __forceinline__ void gate_chain(float* v, const float* lq, float ssl_q,
                                           const float* lmb, float ssl_b,
                                           float K, float sqrtK, float rsqK, float* sig) {
  float ssv = sq4w(v);
  float m0, ssm;
  expmap0c_(v, ssv, K, sqrtK, rsqK, m0, ssm);
  maddc_(m0, v, ssm, lq, ssl_q, K, sqrtK, rsqK);
  madds_(m0, v, ssm, lmb, ssl_b, K, sqrtK, rsqK);
  float c = logc_(m0, ssm, sqrtK, rsqK);
#pragma unroll
  for (int e = 0; e < 4; ++e) sig[e] = frcp(1.0f + __expf(-c * v[e]));
}

// ---------------- pack weights: uint4[k4*768+col] = 4x half2 ----------------
__global__ void pack_weights(const float* __restrict__ wih, const float* __restrict__ whh,
                             uint4* __restrict__ Pih, uint4* __restrict__ Phh) {
  int idx = blockIdx.x * 256 + threadIdx.x;
  int m   = idx / 24576;
  int rem = idx % 24576;
  int k4  = rem / 768;
  int col = rem % 768;
  int g   = col >> 8;
  int j   = col & 255;
  int gsrc = (g == 0) ? 2 : ((g == 1) ? 0 : 1);
  const float* src = (m == 0) ? wih : whh;
  const float* row = src + (size_t)(gsrc * H1_ + 1 + j) * H1_ + 1 + 8 * k4;
  uint4 o;
  o.x = pkh(row[0], row[1]);
  o.y = pkh(row[2], row[3]);
  o.z = pkh(row[4], row[5]);
  o.w = pkh(row[6], row[7]);
  ((m == 0) ? Pih : Phh)[(size_t)k4 * 768 + col] = o;
}

// ---------------- precompute xU[t*64+b][768] = x_row @ U^T ----------------
__global__ void precompute_xu(const float* __restrict__ x, const uint4* __restrict__ U4,
                              float* __restrict__ xU) {
  __shared__ __align__(16) uint32_t xp[8][128];
  const int tid = threadIdx.x;
  const int row0 = blockIdx.x * 8;
#pragma unroll
  for (int it = 0; it < 4; ++it) {
    int item = it * 256 + tid;
    int r = item >> 7, i = item & 127;
    int row = row0 + r;
    int t = row >> 6, bb = row & 63;
    const float* xr = x + ((size_t)bb * T_ + t) * 256;
    float2 xv = ((const float2*)xr)[i];
    xp[r][i] = pkh(xv.x, xv.y);
  }
  __syncthreads();
  float acc[8][3];
#pragma unroll
  for (int r = 0; r < 8; ++r)
#pragma unroll
    for (int c = 0; c < 3; ++c) acc[r][c] = 0.f;

#pragma unroll 2
  for (int k4 = 0; k4 < 32; ++k4) {
    uint4 w0 = U4[(size_t)k4 * 768 + tid];
    uint4 w1 = U4[(size_t)k4 * 768 + 256 + tid];
    uint4 w2 = U4[(size_t)k4 * 768 + 512 + tid];
#pragma unroll
    for (int r = 0; r < 8; ++r) {
      uint4 gp = ((const uint4*)xp[r])[k4];
      acc[r][0] = fdot2(w0.x, gp.x, acc[r][0]); acc[r][0] = fdot2(w0.y, gp.y, acc[r][0]);
      acc[r][0] = fdot2(w0.z, gp.z, acc[r][0]); acc[r][0] = fdot2(w0.w, gp.w, acc[r][0]);
      acc[r][1] = fdot2(w1.x, gp.x, acc[r][1]); acc[r][1] = fdot2(w1.y, gp.y, acc[r][1]);
      acc[r][1] = fdot2(w1.z, gp.z, acc[r][1]); acc[r][1] = fdot2(w1.w, gp.w, acc[r][1]);
      acc[r][2] = fdot2(w2.x, gp.x, acc[r][2]); acc[r][2] = fdot2(w2.y, gp.y, acc[r][2]);
      acc[r][2] = fdot2(w2.z, gp.z, acc[r][2]); acc[r][2] = fdot2(w2.w, gp.w, acc[r][2]);
    }
  }
#pragma unroll
  for (int r = 0; r < 8; ++r)
#pragma unroll
    for (int c = 0; c < 3; ++c)
      xU[(size_t)(row0 + r) * 768 + c * 256 + tid] = acc[r][c];
}

// ---------------- xUss[row*3+g] = |xU_row_gate|^2 ----------------
__global__ void xuss_kernel(const float* __restrict__ xU, float* __restrict__ xUss) {
  int row  = (blockIdx.x * 256 + threadIdx.x) >> 6;
  int lane = threadIdx.x & 63;
  const float4* base = (const float4*)(xU + (size_t)row * 768);
#pragma unroll
  for (int g = 0; g < 3; ++g) {
    float4 v = base[g * 64 + lane];
    float s = wsum(v.x*v.x + v.y*v.y + v.z*v.z + v.w*v.w);
    if (lane == 0) xUss[(size_t)row * 3 + g] = s;
  }
}

// ---------------- sequential scan, one WG per batch row ----------------
// Serial chains de-duplicated: r-chain on wave 0 (SIMD0), z-chain on wave 1
// (SIMD1, parallel), h-chain on wave 0. GEMVs use all 512 threads.
__global__ __launch_bounds__(512, 2) void mobius_gru_scan(
    const float* __restrict__ xU, const float* __restrict__ xUss,
    const uint4* __restrict__ W4, const float* __restrict__ bias,
    const float* __restrict__ kin, float* __restrict__ out) {
  __shared__ __align__(16) uint32_t lds_gp[128];   // packed g vector (256 halves)
  __shared__ __align__(16) float lds_v[512];       // GEMV1 results [z | r]
  __shared__ __align__(16) float lds_v2[512];      // GEMV2 split-K partials
  __shared__ __align__(16) float lds_xu[768];      // lq rows [z | r | h]
  __shared__ __align__(16) float lds_zg[256];      // z gate

  const int tid  = threadIdx.x;
  const int lane = tid & 63;
  const int wave = tid >> 6;
  const int b    = blockIdx.x;

  const float kk    = kin[0];
  const float K     = 1.0f / kk;
  const float sqrtK = sqrtf(K);
  const float rsqK  = 1.0f / sqrtK;

  // bias tangent = spatial part (logmap0(expmap0(b)) == b); |b|^2 per gate
  float lmeb[3][4]; float sslb[3];
  {
    const int rows[3] = {2, 0, 1};   // z, r, h
#pragma unroll
    for (int g = 0; g < 3; ++g) {
#pragma unroll
      for (int e = 0; e < 4; ++e) lmeb[g][e] = bias[rows[g] * H1_ + 1 + 4 * lane + e];
      sslb[g] = sq4w(lmeb[g]);
    }
  }

  float h0c = 0.f, hs[4] = {0.f, 0.f, 0.f, 0.f}, ssh = 0.f;

  // prefetch t=0 lq row + norms
  float xa, xb, nsv0, nsv1, nsv2;
  {
    const float* xrow = xU + (size_t)b * 768;
    xa = xrow[tid];
    xb = (tid < 256) ? xrow[512 + tid] : 0.f;
    const float* srow = xUss + (size_t)b * 3;
    nsv0 = srow[0]; nsv1 = srow[1]; nsv2 = srow[2];
  }

  float gh[4];   // wave0-valid only

  for (int t = 0; t < T_; ++t) {
    const float s0 = nsv0, s1 = nsv1, s2 = nsv2;

    // gh = logmap0(h) — only wave 0 holds real h
    if (wave == 0) {
      logmap0o_(h0c, hs, ssh, sqrtK, rsqK, gh);
      uint2 p; p.x = pkh(gh[0], gh[1]); p.y = pkh(gh[2], gh[3]);
      ((uint2*)lds_gp)[lane] = p;
    }
    __syncthreads();   // B1

    // ---- phase 1: stage lq row, GEMV1 cols [0,512) = z,r (all threads) ----
    lds_xu[tid] = xa;
    if (tid < 256) lds_xu[512 + tid] = xb;
    {
      float a0 = 0.f, a1 = 0.f, a2 = 0.f, a3 = 0.f;
#pragma unroll 4
      for (int k4 = 0; k4 < 32; ++k4) {
        uint4 w  = W4[(size_t)k4 * 768 + tid];
        uint4 gp = ((const uint4*)lds_gp)[k4];
        a0 = fdot2(w.x, gp.x, a0);
        a1 = fdot2(w.y, gp.y, a1);
        a2 = fdot2(w.z, gp.z, a2);
        a3 = fdot2(w.w, gp.w, a3);
      }
      lds_v[tid] = (a0 + a1) + (a2 + a3);
    }
    if (t + 1 < T_) {   // prefetch next step
      const float* nx = xU + (size_t)((t + 1) * B_ + b) * 768;
      xa = nx[tid];
      xb = (tid < 256) ? nx[512 + tid] : 0.f;
      const float* srow = xUss + (size_t)((t + 1) * B_ + b) * 3;
      nsv0 = srow[0]; nsv1 = srow[1]; nsv2 = srow[2];
    }
    __syncthreads();   // B2

    if (wave == 0) {
      // ---- r-gate chain + rh_t (critical path, SIMD0 exclusively) ----
      float v[4], xv[4];
      { float4 t4 = ((const float4*)lds_v)[64 + lane];  v[0]=t4.x; v[1]=t4.y; v[2]=t4.z; v[3]=t4.w; }
      { float4 t4 = ((const float4*)lds_xu)[64 + lane]; xv[0]=t4.x; xv[1]=t4.y; xv[2]=t4.z; xv[3]=t4.w; }
      float rg[4];
      gate_chain(v, xv, s1, lmeb[1], sslb[1], K, sqrtK, rsqK, rg);
      float rhu[4];
#pragma unroll
      for (int e = 0; e < 4; ++e) rhu[e] = rg[e] * gh[e];
      float ssrh = sq4w(rhu);
      float r0, ssr;
      expmap0c_(rhu, ssrh, K, sqrtK, rsqK, r0, ssr);
      float lrh[4];
      logmap0o_(r0, rhu, ssr, sqrtK, rsqK, lrh);
      uint2 p; p.x = pkh(lrh[0], lrh[1]); p.y = pkh(lrh[2], lrh[3]);
      ((uint2*)lds_gp)[lane] = p;
    } else if (wave == 1) {
      // ---- z-gate chain (SIMD1, parallel with r-chain) ----
      float v[4], xv[4];
      { float4 t4 = ((const float4*)lds_v)[lane];  v[0]=t4.x; v[1]=t4.y; v[2]=t4.z; v[3]=t4.w; }
      { float4 t4 = ((const float4*)lds_xu)[lane]; xv[0]=t4.x; xv[1]=t4.y; xv[2]=t4.z; xv[3]=t4.w; }
      float zg[4];
      gate_chain(v, xv, s0, lmeb[0], sslb[0], K, sqrtK, rsqK, zg);
      float4 z4 = {zg[0], zg[1], zg[2], zg[3]};
      ((float4*)lds_zg)[lane] = z4;
    }
    __syncthreads();   // B3

    // ---- phase 2: GEMV2 cols h, split-K over 512 threads ----
    {
      int j  = tid & 255;
      int kh = tid >> 8;
      float a0 = 0.f, a1 = 0.f, a2 = 0.f, a3 = 0.f;
#pragma unroll 4
      for (int k4 = kh * 16; k4 < kh * 16 + 16; ++k4) {
        uint4 w  = W4[(size_t)k4 * 768 + 512 + j];
        uint4 gp = ((const uint4*)lds_gp)[k4];
        a0 = fdot2(w.x, gp.x, a0);
        a1 = fdot2(w.y, gp.y, a1);
        a2 = fdot2(w.z, gp.z, a2);
        a3 = fdot2(w.w, gp.w, a3);
      }
      lds_v2[kh * 256 + j] = (a0 + a1) + (a2 + a3);
    }
    __syncthreads();   // B4

    if (wave == 0) {
      // ---- h_tilde chain (wave 0 only) ----
      float t0, ts[4], sst;
      {
        float4 pa = ((const float4*)lds_v2)[lane];
        float4 pb = ((const float4*)lds_v2)[64 + lane];
        ts[0] = pa.x + pb.x; ts[1] = pa.y + pb.y; ts[2] = pa.z + pb.z; ts[3] = pa.w + pb.w;
        float xv[4];
        { float4 t4 = ((const float4*)lds_xu)[128 + lane]; xv[0]=t4.x; xv[1]=t4.y; xv[2]=t4.z; xv[3]=t4.w; }
        float ssv = sq4w(ts);
        expmap0c_(ts, ssv, K, sqrtK, rsqK, t0, sst);
        maddc_(t0, ts, sst, xv, s2, K, sqrtK, rsqK);
        madds_(t0, ts, sst, lmeb[2], sslb[2], K, sqrtK, rsqK);
      }

      // ---- delta_h = mobius_add(proj(-hx), h_tilde) ----
      float n0, ns[4], ssn = ssh;
#pragma unroll
      for (int e = 0; e < 4; ++e) ns[e] = -hs[e];
      n0 = sqrtf(fmaxf(K + ssh, 1e-7f));
      float lt[4], sslt;
      logmap0c_(t0, ts, sst, K, sqrtK, rsqK, lt, sslt);
      maddc_(n0, ns, ssn, lt, sslt, K, sqrtK, rsqK);

      // ---- h_new = expmap(ptransp0(hx, z*logmap0(delta_h)), hx) ----
      float ld[4];
      logmap0o_(n0, ns, ssn, sqrtK, rsqK, ld);
      float uu[4];
      {
        float4 z4 = ((const float4*)lds_zg)[lane];
        uu[0] = z4.x * ld[0]; uu[1] = z4.y * ld[1]; uu[2] = z4.z * ld[2]; uu[3] = z4.w * ld[3];
      }
      float ssuu = sq4w(uu);
      maddc_(h0c, hs, ssh, uu, ssuu, K, sqrtK, rsqK);

      float* orow = out + (size_t)(t * B_ + b) * H1_;
      if (lane == 0) orow[0] = h0c;
#pragma unroll
      for (int e = 0; e < 4; ++e) orow[1 + 4 * lane + e] = hs[e];
    }
  }

  if (wave == 0) {
    float4 hv = {hs[0], hs[1], hs[2], hs[3]};
    ((float4*)(out + (size_t)T_ * B_ * H1_ + (size_t)b * 256))[lane] = hv;
  }
}

// ---------------- launch ----------------
extern "C" void kernel_launch(void* const* d_in, const int* in_sizes, int n_in,
                              void* d_out, int out_size, void* d_ws, size_t ws_size,
                              hipStream_t stream) {
  const float* x    = (const float*)d_in[0];
  const float* k    = (const float*)d_in[1];
  const float* wih  = (const float*)d_in[2];
  const float* whh  = (const float*)d_in[3];
  const float* bias = (const float*)d_in[4];
  float* out = (float*)d_out;

  // ws: Pih (24576 uint4, later overlaid by xUss) | Phh (24576 uint4) | xU (32768*768 f)
  uint4* Pih = (uint4*)d_ws;
  uint4* Phh = Pih + 24576;
  float* xU  = (float*)(Phh + 24576);
  float* xUss = (float*)Pih;   // Pih dead after precompute_xu

  pack_weights<<<192, 256, 0, stream>>>(wih, whh, Pih, Phh);
  precompute_xu<<<4096, 256, 0, stream>>>(x, Pih, xU);
  xuss_kernel<<<8192, 256, 0, stream>>>(xU, xUss);
  mobius_gru_scan<<<B_, 512, 0, stream>>>(xU, xUss, Phh, bias, k, out);
}

// Round 7
// 2771.611 us; speedup vs baseline: 6.3051x; 1.1391x over previous
//
#include <hip/hip_runtime.h>
#include <hip/hip_fp16.h>
#include <stdint.h>

#define B_  64
#define T_  512
#define H1_ 257

typedef _Float16 h2v __attribute__((ext_vector_type(2)));

__device__ __forceinline__ float frcp(float x) { return __builtin_amdgcn_rcpf(x); }
__device__ __forceinline__ float frsq(float x) { return __builtin_amdgcn_rsqf(x); }
__device__ __forceinline__ h2v u2h(uint32_t u) { return __builtin_bit_cast(h2v, u); }
__device__ __forceinline__ float fdot2(uint32_t a, uint32_t b, float c) {
  return __builtin_amdgcn_fdot2(u2h(a), u2h(b), c, false);
}
__device__ __forceinline__ uint32_t pkh(float a, float b) {
  __half2 h = __halves2half2(__float2half(a), __float2half(b));
  return __builtin_bit_cast(uint32_t, h);
}

// raw barrier: orders LDS (lgkmcnt) but does NOT drain vmcnt — global loads/
// stores stay in flight across it; their consumers get compiler-inserted waits.
#define LDS_BAR() do { \
  asm volatile("s_waitcnt lgkmcnt(0)" ::: "memory"); \
  __builtin_amdgcn_s_barrier(); \
  asm volatile("" ::: "memory"); \
} while (0)

// ---- DPP wave64 sum, broadcast via readlane ----
template <int CTRL>
__device__ __forceinline__ float dpp_add(float v) {
  int t = __builtin_amdgcn_update_dpp(0, __builtin_bit_cast(int, v), CTRL, 0xf, 0xf, true);
  return v + __builtin_bit_cast(float, t);
}
__device__ __forceinline__ float wsum(float v) {
  v = dpp_add<0xB1>(v);    // quad_perm [1,0,3,2]
  v = dpp_add<0x4E>(v);    // quad_perm [2,3,0,1]
  v = dpp_add<0x141>(v);   // row_half_mirror
  v = dpp_add<0x140>(v);   // row_mirror -> 16-lane-row sums
  int xi = __builtin_bit_cast(int, v);
  float a = __builtin_bit_cast(float, __builtin_amdgcn_readlane(xi, 0));
  float b = __builtin_bit_cast(float, __builtin_amdgcn_readlane(xi, 16));
  float c = __builtin_bit_cast(float, __builtin_amdgcn_readlane(xi, 32));
  float d = __builtin_bit_cast(float, __builtin_amdgcn_readlane(xi, 48));
  return (a + b) + (c + d);
}
__device__ __forceinline__ float sq4w(const float* s) {
  return wsum(s[0]*s[0] + s[1]*s[1] + s[2]*s[2] + s[3]*s[3]);
}
__device__ __forceinline__ float dot4w(const float* a, const float* b) {
  return wsum(a[0]*b[0] + a[1]*b[1] + a[2]*b[2] + a[3]*b[3]);
}

// logmap0 spatial: o = c*s. ss must be TRUE |s|^2.
__device__ __forceinline__ float logc_(float x0, float ss, float sqrtK, float rsqK) {
  float yn = sqrtf(fmaxf(ss, 1e-30f));
  float th = fmaxf(x0 * rsqK, 1.0f + 1e-7f);
  float ac = __logf(th + sqrtf(th*th - 1.0f));
  return sqrtK * ac * frcp(yn);
}
__device__ __forceinline__ void logmap0o_(float x0, const float* s, float ss,
                                          float sqrtK, float rsqK, float* o) {
  float c = logc_(x0, ss, sqrtK, rsqK);
#pragma unroll
  for (int e = 0; e < 4; ++e) o[e] = c * s[e];
}
__device__ __forceinline__ void logmap0c_(float x0, const float* s, float ss,
                                          float K, float sqrtK, float rsqK,
                                          float* o, float& sso) {
  float yn = sqrtf(fmaxf(ss, 1e-30f));
  float th = fmaxf(x0 * rsqK, 1.0f + 1e-7f);
  float ac = __logf(th + sqrtf(th*th - 1.0f));
  float c  = sqrtK * ac * frcp(yn);
#pragma unroll
  for (int e = 0; e < 4; ++e) o[e] = c * s[e];
  sso = K * ac * ac;
}

// expmap0+proj, in-place u->s; single scale => ss_s safe algebraic
__device__ __forceinline__ void expmap0c_(float* u, float ss_u, float K, float sqrtK,
                                          float rsqK, float& x0, float& ss_s) {
  float sn = sqrtf(fmaxf(ss_u, 1e-30f));
  float th = sn * rsqK;
  float ex = __expf(th), ei = frcp(ex);
  float sh = 0.5f * (ex - ei);
  float c  = sqrtK * sh * frcp(sn);
#pragma unroll
  for (int e = 0; e < 4; ++e) u[e] = c * u[e];
  float t = sqrtK * sh;
  ss_s = t * t;
  x0 = sqrtf(fmaxf(K + ss_s, 1e-7f));
}

// mobius-add core: X <- proj(expmap(proj_tan(ptransp0(X,lm)),X)). 2 wsums.
__device__ __forceinline__ void maddc_(float& x0, float* xs, float& ss,
                                       const float* lm, float ssl,
                                       float K, float sqrtK, float rsqK) {
  float inv = frsq(fmaxf(ss, 1e-30f));
  float dotXL = dot4w(xs, lm);
  float alpha = inv * dotXL * rsqK;
  float c2 = alpha * (sqrtK - x0);
  float ciw = c2 * inv;
  float w[4];
#pragma unroll
  for (int e = 0; e < 4; ++e) w[e] = lm[e] - ciw * xs[e];
  float ux = dotXL - ciw * ss;
  float w0 = ux * frcp(fmaxf(x0, 1e-7f));
  float ssw = fmaxf(ssl - 2.0f*ciw*dotXL + ciw*ciw*ss, 0.0f);
  float md = ssw - w0 * w0;
  float mn = sqrtf(fmaxf(md, 1e-7f));
  float th = fmaxf(fminf(mn, 1e6f) * rsqK, 1e-15f);
  float ex = __expf(th), ei = frcp(ex);
  float ch = 0.5f * (ex + ei);
  float sh = 0.5f * (ex - ei) * frcp(th);
#pragma unroll
  for (int e = 0; e < 4; ++e) xs[e] = ch * xs[e] + sh * w[e];
  ss = sq4w(xs);                       // TRUE norm^2 (R5 NaN fix)
  x0 = sqrtf(fmaxf(K + ss, 1e-7f));
}

// small-theta mobius-add (bias): no cancellation, algebraic ss carry safe
__device__ __forceinline__ void madds_(float& x0, float* xs, float& ss,
                                       const float* lm, float ssl,
                                       float K, float sqrtK, float rsqK) {
  float inv = frsq(fmaxf(ss, 1e-30f));
  float dotXL = dot4w(xs, lm);
  float alpha = inv * dotXL * rsqK;
  float c2 = alpha * (sqrtK - x0);
  float ciw = c2 * inv;
  float ux = dotXL - ciw * ss;
  float ssw = fmaxf(ssl - 2.0f*ciw*dotXL + ciw*ciw*ss, 0.0f);
  float nss = ss + 2.0f*ux + ssw;
#pragma unroll
  for (int e = 0; e < 4; ++e) xs[e] += lm[e] - ciw * xs[e];
  ss = fmaxf(nss, 0.0f);
  x0 = sqrtf(fmaxf(K + ss, 1e-7f));
}

// gate: v (GEMV out), lq (=xU), bias lm; -> sigmoid(logmap0(chain))
__device__ __forceinline__ void gate_chain(float* v, const float* lq, float ssl_q,
                                           const float* lmb, float ssl_b,
                                           float K, float sqrtK, float rsqK, float* sig) {
  float ssv = sq4w(v);
  float m0, ssm;
  expmap0c_(v, ssv, K, sqrtK, rsqK, m0, ssm);
  maddc_(m0, v, ssm, lq, ssl_q, K, sqrtK, rsqK);
  madds_(m0, v, ssm, lmb, ssl_b, K, sqrtK, rsqK);
  float c = logc_(m0, ssm, sqrtK, rsqK);
#pragma unroll
  for (int e = 0; e < 4; ++e) sig[e] = frcp(1.0f + __expf(-c * v[e]));
}

// ---------------- pack weights: uint4[k4*768+col] = 4x half2 ----------------
__global__ void pack_weights(const float* __restrict__ wih, const float* __restrict__ whh,
                             uint4* __restrict__ Pih, uint4* __restrict__ Phh) {
  int idx = blockIdx.x * 256 + threadIdx.x;
  int m   = idx / 24576;
  int rem = idx % 24576;
  int k4  = rem / 768;
  int col = rem % 768;
  int g   = col >> 8;
  int j   = col & 255;
  int gsrc = (g == 0) ? 2 : ((g == 1) ? 0 : 1);
  const float* src = (m == 0) ? wih : whh;
  const float* row = src + (size_t)(gsrc * H1_ + 1 + j) * H1_ + 1 + 8 * k4;
  uint4 o;
  o.x = pkh(row[0], row[1]);
  o.y = pkh(row[2], row[3]);
  o.z = pkh(row[4], row[5]);
  o.w = pkh(row[6], row[7]);
  ((m == 0) ? Pih : Phh)[(size_t)k4 * 768 + col] = o;
}

// ---------------- precompute xU[t*64+b][768] = x_row @ U^T ----------------
__global__ void precompute_xu(const float* __restrict__ x, const uint4* __restrict__ U4,
                              float* __restrict__ xU) {
  __shared__ __align__(16) uint32_t xp[8][128];
  const int tid = threadIdx.x;
  const int row0 = blockIdx.x * 8;
#pragma unroll
  for (int it = 0; it < 4; ++it) {
    int item = it * 256 + tid;
    int r = item >> 7, i = item & 127;
    int row = row0 + r;
    int t = row >> 6, bb = row & 63;
    const float* xr = x + ((size_t)bb * T_ + t) * 256;
    float2 xv = ((const float2*)xr)[i];
    xp[r][i] = pkh(xv.x, xv.y);
  }
  __syncthreads();
  float acc[8][3];
#pragma unroll
  for (int r = 0; r < 8; ++r)
#pragma unroll
    for (int c = 0; c < 3; ++c) acc[r][c] = 0.f;

#pragma unroll 2
  for (int k4 = 0; k4 < 32; ++k4) {
    uint4 w0 = U4[(size_t)k4 * 768 + tid];
    uint4 w1 = U4[(size_t)k4 * 768 + 256 + tid];
    uint4 w2 = U4[(size_t)k4 * 768 + 512 + tid];
#pragma unroll
    for (int r = 0; r < 8; ++r) {
      uint4 gp = ((const uint4*)xp[r])[k4];
      acc[r][0] = fdot2(w0.x, gp.x, acc[r][0]); acc[r][0] = fdot2(w0.y, gp.y, acc[r][0]);
      acc[r][0] = fdot2(w0.z, gp.z, acc[r][0]); acc[r][0] = fdot2(w0.w, gp.w, acc[r][0]);
      acc[r][1] = fdot2(w1.x, gp.x, acc[r][1]); acc[r][1] = fdot2(w1.y, gp.y, acc[r][1]);
      acc[r][1] = fdot2(w1.z, gp.z, acc[r][1]); acc[r][1] = fdot2(w1.w, gp.w, acc[r][1]);
      acc[r][2] = fdot2(w2.x, gp.x, acc[r][2]); acc[r][2] = fdot2(w2.y, gp.y, acc[r][2]);
      acc[r][2] = fdot2(w2.z, gp.z, acc[r][2]); acc[r][2] = fdot2(w2.w, gp.w, acc[r][2]);
    }
  }
#pragma unroll
  for (int r = 0; r < 8; ++r)
#pragma unroll
    for (int c = 0; c < 3; ++c)
      xU[(size_t)(row0 + r) * 768 + c * 256 + tid] = acc[r][c];
}

// ---------------- xUss[row*3+g] = |xU_row_gate|^2 ----------------
__global__ void xuss_kernel(const float* __restrict__ xU, float* __restrict__ xUss) {
  int row  = (blockIdx.x * 256 + threadIdx.x) >> 6;
  int lane = threadIdx.x & 63;
  const float4* base = (const float4*)(xU + (size_t)row * 768);
#pragma unroll
  for (int g = 0; g < 3; ++g) {
    float4 v = base[g * 64 + lane];
    float s = wsum(v.x*v.x + v.y*v.y + v.z*v.z + v.w*v.w);
    if (lane == 0) xUss[(size_t)row * 3 + g] = s;
  }
}

// ---------------- sequential scan, one WG per batch row ----------------
// W_h staged in LDS (128 KB) -> GEMV2 off the vector-memory path.
// Raw barriers (no vmcnt drain) let prefetch/stores fly across the step.
__global__ __launch_bounds__(512, 1) void mobius_gru_scan(
    const float* __restrict__ xU, const float* __restrict__ xUss,
    const uint4* __restrict__ W4, const float* __restrict__ bias,
    const float* __restrict__ kin, float* __restrict__ out) {
  __shared__ __align__(16) uint4 LWH[32][256];     // 128 KB: h-gate weights
  __shared__ __align__(16) uint32_t lds_gp[128];   // packed g vector (256 halves)
  __shared__ __align__(16) float lds_v[512];       // GEMV1 results [z | r]
  __shared__ __align__(16) float lds_v2[512];      // GEMV2 split-K partials
  __shared__ __align__(16) float lds_xu[768];      // lq rows [z | r | h]
  __shared__ __align__(16) float lds_zg[256];      // z gate

  const int tid  = threadIdx.x;
  const int lane = tid & 63;
  const int wave = tid >> 6;
  const int b    = blockIdx.x;

  const float kk    = kin[0];
  const float K     = 1.0f / kk;
  const float sqrtK = sqrtf(K);
  const float rsqK  = 1.0f / sqrtK;

  // ---- stage W_h (cols 512..767 of W4) into LDS, once ----
#pragma unroll
  for (int it = 0; it < 16; ++it) {
    int idx = it * 512 + tid;
    int k4 = idx >> 8, j = idx & 255;
    LWH[k4][j] = W4[(size_t)k4 * 768 + 512 + j];
  }

  // bias tangent = spatial part (logmap0(expmap0(b)) == b); |b|^2 per gate
  float lmeb[3][4]; float sslb[3];
  {
    const int rows[3] = {2, 0, 1};   // z, r, h
#pragma unroll
    for (int g = 0; g < 3; ++g) {
#pragma unroll
      for (int e = 0; e < 4; ++e) lmeb[g][e] = bias[rows[g] * H1_ + 1 + 4 * lane + e];
      sslb[g] = sq4w(lmeb[g]);
    }
  }

  float h0c = 0.f, hs[4] = {0.f, 0.f, 0.f, 0.f}, ssh = 0.f;

  // prefetch t=0 lq row + norms
  float xa, xb, nsv0, nsv1, nsv2;
  {
    const float* xrow = xU + (size_t)b * 768;
    xa = xrow[tid];
    xb = (tid < 256) ? xrow[512 + tid] : 0.f;
    const float* srow = xUss + (size_t)b * 3;
    nsv0 = srow[0]; nsv1 = srow[1]; nsv2 = srow[2];
  }

  __syncthreads();   // full barrier once: staging visible to all

  float gh[4];       // wave0-valid only

  for (int t = 0; t < T_; ++t) {
    const float s0 = nsv0, s1 = nsv1, s2 = nsv2;

    // gh = logmap0(h) — only wave 0 holds real h
    if (wave == 0) {
      logmap0o_(h0c, hs, ssh, sqrtK, rsqK, gh);
      uint2 p; p.x = pkh(gh[0], gh[1]); p.y = pkh(gh[2], gh[3]);
      ((uint2*)lds_gp)[lane] = p;
    }
    LDS_BAR();   // B1

    // ---- phase 1: stage lq row, prefetch next, GEMV1 cols [0,512) ----
    lds_xu[tid] = xa;
    if (tid < 256) lds_xu[512 + tid] = xb;
    if (t + 1 < T_) {   // issue next-step loads early; consumed next step
      const float* nx = xU + (size_t)((t + 1) * B_ + b) * 768;
      xa = nx[tid];
      xb = (tid < 256) ? nx[512 + tid] : 0.f;
      const float* srow = xUss + (size_t)((t + 1) * B_ + b) * 3;
      nsv0 = srow[0]; nsv1 = srow[1]; nsv2 = srow[2];
    }
    {
      const uint4* wp = W4 + tid;
      float a0 = 0.f, a1 = 0.f, a2 = 0.f, a3 = 0.f;
#pragma unroll 4
      for (int k4 = 0; k4 < 32; ++k4) {
        uint4 w  = wp[(size_t)k4 * 768];
        uint4 gp = ((const uint4*)lds_gp)[k4];
        a0 = fdot2(w.x, gp.x, a0);
        a1 = fdot2(w.y, gp.y, a1);
        a2 = fdot2(w.z, gp.z, a2);
        a3 = fdot2(w.w, gp.w, a3);
      }
      lds_v[tid] = (a0 + a1) + (a2 + a3);
    }
    LDS_BAR();   // B2

    if (wave == 0) {
      // ---- r-gate chain (critical path, SIMD0) ----
      float v[4], xv[4];
      { float4 t4 = ((const float4*)lds_v)[64 + lane];  v[0]=t4.x; v[1]=t4.y; v[2]=t4.z; v[3]=t4.w; }
      { float4 t4 = ((const float4*)lds_xu)[64 + lane]; xv[0]=t4.x; xv[1]=t4.y; xv[2]=t4.z; xv[3]=t4.w; }
      float rg[4];
      gate_chain(v, xv, s1, lmeb[1], sslb[1], K, sqrtK, rsqK, rg);
      // lrh = logmap0(expmap0(r*gh)) == r*gh exactly
      uint2 p;
      p.x = pkh(rg[0] * gh[0], rg[1] * gh[1]);
      p.y = pkh(rg[2] * gh[2], rg[3] * gh[3]);
      ((uint2*)lds_gp)[lane] = p;
    } else if (wave == 1) {
      // ---- z-gate chain (SIMD1, parallel with r-chain) ----
      float v[4], xv[4];
      { float4 t4 = ((const float4*)lds_v)[lane];  v[0]=t4.x; v[1]=t4.y; v[2]=t4.z; v[3]=t4.w; }
      { float4 t4 = ((const float4*)lds_xu)[lane]; xv[0]=t4.x; xv[1]=t4.y; xv[2]=t4.z; xv[3]=t4.w; }
      float zg[4];
      gate_chain(v, xv, s0, lmeb[0], sslb[0], K, sqrtK, rsqK, zg);
      float4 z4 = {zg[0], zg[1], zg[2], zg[3]};
      ((float4*)lds_zg)[lane] = z4;
    }
    LDS_BAR();   // B3

    // ---- phase 2: GEMV2 (h gate) from LDS weights, split-K over 512 ----
    {
      int j  = tid & 255;
      int kh = tid >> 8;
      const uint4* wl = &LWH[kh * 16][j];
      float a0 = 0.f, a1 = 0.f, a2 = 0.f, a3 = 0.f;
#pragma unroll
      for (int i = 0; i < 16; ++i) {
        uint4 w  = wl[(size_t)i * 256];                 // ds_read_b128, imm offset
        uint4 gp = ((const uint4*)lds_gp)[kh * 16 + i];
        a0 = fdot2(w.x, gp.x, a0);
        a1 = fdot2(w.y, gp.y, a1);
        a2 = fdot2(w.z, gp.z, a2);
        a3 = fdot2(w.w, gp.w, a3);
      }
      lds_v2[kh * 256 + j] = (a0 + a1) + (a2 + a3);
    }
    LDS_BAR();   // B4

    if (wave == 0) {
      // ---- h_tilde chain ----
      float t0, ts[4], sst;
      {
        float4 pa = ((const float4*)lds_v2)[lane];
        float4 pb = ((const float4*)lds_v2)[64 + lane];
        ts[0] = pa.x + pb.x; ts[1] = pa.y + pb.y; ts[2] = pa.z + pb.z; ts[3] = pa.w + pb.w;
        float xv[4];
        { float4 t4 = ((const float4*)lds_xu)[128 + lane]; xv[0]=t4.x; xv[1]=t4.y; xv[2]=t4.z; xv[3]=t4.w; }
        float ssv = sq4w(ts);
        expmap0c_(ts, ssv, K, sqrtK, rsqK, t0, sst);
        maddc_(t0, ts, sst, xv, s2, K, sqrtK, rsqK);
        madds_(t0, ts, sst, lmeb[2], sslb[2], K, sqrtK, rsqK);
      }

      // ---- delta_h = mobius_add(proj(-hx), h_tilde) ----
      float n0, ns[4], ssn = ssh;
#pragma unroll
      for (int e = 0; e < 4; ++e) ns[e] = -hs[e];
      n0 = sqrtf(fmaxf(K + ssh, 1e-7f));
      float lt[4], sslt;
      logmap0c_(t0, ts, sst, K, sqrtK, rsqK, lt, sslt);
      maddc_(n0, ns, ssn, lt, sslt, K, sqrtK, rsqK);

      // ---- h_new = expmap(ptransp0(hx, z*logmap0(delta_h)), hx) ----
      float ld[4];
      logmap0o_(n0, ns, ssn, sqrtK, rsqK, ld);
      float uu[4];
      {
        float4 z4 = ((const float4*)lds_zg)[lane];
        uu[0] = z4.x * ld[0]; uu[1] = z4.y * ld[1]; uu[2] = z4.z * ld[2]; uu[3] = z4.w * ld[3];
      }
      float ssuu = sq4w(uu);
      maddc_(h0c, hs, ssh, uu, ssuu, K, sqrtK, rsqK);

      float* orow = out + (size_t)(t * B_ + b) * H1_;
      if (lane == 0) orow[0] = h0c;
#pragma unroll
      for (int e = 0; e < 4; ++e) orow[1 + 4 * lane + e] = hs[e];
    }
  }

  if (wave == 0) {
    float4 hv = {hs[0], hs[1], hs[2], hs[3]};
    ((float4*)(out + (size_t)T_ * B_ * H1_ + (size_t)b * 256))[lane] = hv;
  }
}

// ---------------- launch ----------------
extern "C" void kernel_launch(void* const* d_in, const int* in_sizes, int n_in,
                              void* d_out, int out_size, void* d_ws, size_t ws_size,
                              hipStream_t stream) {
  const float* x    = (const float*)d_in[0];
  const float* k    = (const float*)d_in[1];
  const float* wih  = (const float*)d_in[2];
  const float* whh  = (const float*)d_in[3];
  const float* bias = (const float*)d_in[4];
  float* out = (float*)d_out;

  // ws: Pih (24576 uint4, later overlaid by xUss) | Phh (24576 uint4) | xU (32768*768 f)
  uint4* Pih = (uint4*)d_ws;
  uint4* Phh = Pih + 24576;
  float* xU  = (float*)(Phh + 24576);
  float* xUss = (float*)Pih;   // Pih dead after precompute_xu

  pack_weights<<<192, 256, 0, stream>>>(wih, whh, Pih, Phh);
  precompute_xu<<<4096, 256, 0, stream>>>(x, Pih, xU);
  xuss_kernel<<<8192, 256, 0, stream>>>(xU, xUss);
  mobius_gru_scan<<<B_, 512, 0, stream>>>(xU, xUss, Phh, bias, k, out);
}

// Round 8
// 2010.030 us; speedup vs baseline: 8.6941x; 1.3789x over previous
//
#include <hip/hip_runtime.h>
#include <hip/hip_fp16.h>
#include <stdint.h>

#define B_  64
#define T_  512
#define H1_ 257

typedef _Float16 h2v __attribute__((ext_vector_type(2)));

__device__ __forceinline__ float frcp(float x) { return __builtin_amdgcn_rcpf(x); }
__device__ __forceinline__ float frsq(float x) { return __builtin_amdgcn_rsqf(x); }
__device__ __forceinline__ h2v u2h(uint32_t u) { return __builtin_bit_cast(h2v, u); }
__device__ __forceinline__ float fdot2(uint32_t a, uint32_t b, float c) {
  return __builtin_amdgcn_fdot2(u2h(a), u2h(b), c, false);
}
__device__ __forceinline__ uint32_t pkh(float a, float b) {
  __half2 h = __halves2half2(__float2half(a), __float2half(b));
  return __builtin_bit_cast(uint32_t, h);
}

// raw barrier: orders LDS (lgkmcnt) but does NOT drain vmcnt.
#define LDS_BAR() do { \
  asm volatile("s_waitcnt lgkmcnt(0)" ::: "memory"); \
  __builtin_amdgcn_s_barrier(); \
  asm volatile("" ::: "memory"); \
} while (0)

// ---- DPP wave64 sum, broadcast via readlane ----
template <int CTRL>
__device__ __forceinline__ float dpp_add(float v) {
  int t = __builtin_amdgcn_update_dpp(0, __builtin_bit_cast(int, v), CTRL, 0xf, 0xf, true);
  return v + __builtin_bit_cast(float, t);
}
__device__ __forceinline__ float wsum(float v) {
  v = dpp_add<0xB1>(v);
  v = dpp_add<0x4E>(v);
  v = dpp_add<0x141>(v);
  v = dpp_add<0x140>(v);
  int xi = __builtin_bit_cast(int, v);
  float a = __builtin_bit_cast(float, __builtin_amdgcn_readlane(xi, 0));
  float b = __builtin_bit_cast(float, __builtin_amdgcn_readlane(xi, 16));
  float c = __builtin_bit_cast(float, __builtin_amdgcn_readlane(xi, 32));
  float d = __builtin_bit_cast(float, __builtin_amdgcn_readlane(xi, 48));
  return (a + b) + (c + d);
}
__device__ __forceinline__ float sq4w(const float* s) {
  return wsum(s[0]*s[0] + s[1]*s[1] + s[2]*s[2] + s[3]*s[3]);
}
__device__ __forceinline__ float dot4w(const float* a, const float* b) {
  return wsum(a[0]*b[0] + a[1]*b[1] + a[2]*b[2] + a[3]*b[3]);
}

__device__ __forceinline__ float logc_(float x0, float ss, float sqrtK, float rsqK) {
  float yn = sqrtf(fmaxf(ss, 1e-30f));
  float th = fmaxf(x0 * rsqK, 1.0f + 1e-7f);
  float ac = __logf(th + sqrtf(th*th - 1.0f));
  return sqrtK * ac * frcp(yn);
}
__device__ __forceinline__ void logmap0o_(float x0, const float* s, float ss,
                                          float sqrtK, float rsqK, float* o) {
  float c = logc_(x0, ss, sqrtK, rsqK);
#pragma unroll
  for (int e = 0; e < 4; ++e) o[e] = c * s[e];
}
__device__ __forceinline__ void logmap0c_(float x0, const float* s, float ss,
                                          float K, float sqrtK, float rsqK,
                                          float* o, float& sso) {
  float yn = sqrtf(fmaxf(ss, 1e-30f));
  float th = fmaxf(x0 * rsqK, 1.0f + 1e-7f);
  float ac = __logf(th + sqrtf(th*th - 1.0f));
  float c  = sqrtK * ac * frcp(yn);
#pragma unroll
  for (int e = 0; e < 4; ++e) o[e] = c * s[e];
  sso = K * ac * ac;
}
__device__ __forceinline__ void expmap0c_(float* u, float ss_u, float K, float sqrtK,
                                          float rsqK, float& x0, float& ss_s) {
  float sn = sqrtf(fmaxf(ss_u, 1e-30f));
  float th = sn * rsqK;
  float ex = __expf(th), ei = frcp(ex);
  float sh = 0.5f * (ex - ei);
  float c  = sqrtK * sh * frcp(sn);
#pragma unroll
  for (int e = 0; e < 4; ++e) u[e] = c * u[e];
  float t = sqrtK * sh;
  ss_s = t * t;
  x0 = sqrtf(fmaxf(K + ss_s, 1e-7f));
}
__device__ __forceinline__ void maddc_(float& x0, float* xs, float& ss,
                                       const float* lm, float ssl,
                                       float K, float sqrtK, float rsqK) {
  float inv = frsq(fmaxf(ss, 1e-30f));
  float dotXL = dot4w(xs, lm);
  float alpha = inv * dotXL * rsqK;
  float c2 = alpha * (sqrtK - x0);
  float ciw = c2 * inv;
  float w[4];
#pragma unroll
  for (int e = 0; e < 4; ++e) w[e] = lm[e] - ciw * xs[e];
  float ux = dotXL - ciw * ss;
  float w0 = ux * frcp(fmaxf(x0, 1e-7f));
  float ssw = fmaxf(ssl - 2.0f*ciw*dotXL + ciw*ciw*ss, 0.0f);
  float md = ssw - w0 * w0;
  float mn = sqrtf(fmaxf(md, 1e-7f));
  float th = fmaxf(fminf(mn, 1e6f) * rsqK, 1e-15f);
  float ex = __expf(th), ei = frcp(ex);
  float ch = 0.5f * (ex + ei);
  float sh = 0.5f * (ex - ei) * frcp(th);
#pragma unroll
  for (int e = 0; e < 4; ++e) xs[e] = ch * xs[e] + sh * w[e];
  ss = sq4w(xs);                       // TRUE norm^2 (R5 NaN fix)
  x0 = sqrtf(fmaxf(K + ss, 1e-7f));
}
__device__ __forceinline__ void madds_(float& x0, float* xs, float& ss,
                                       const float* lm, float ssl,
                                       float K, float sqrtK, float rsqK) {
  float inv = frsq(fmaxf(ss, 1e-30f));
  float dotXL = dot4w(xs, lm);
  float alpha = inv * dotXL * rsqK;
  float c2 = alpha * (sqrtK - x0);
  float ciw = c2 * inv;
  float ux = dotXL - ciw * ss;
  float ssw = fmaxf(ssl - 2.0f*ciw*dotXL + ciw*ciw*ss, 0.0f);
  float nss = ss + 2.0f*ux + ssw;
#pragma unroll
  for (int e = 0; e < 4; ++e) xs[e] += lm[e] - ciw * xs[e];
  ss = fmaxf(nss, 0.0f);
  x0 = sqrtf(fmaxf(K + ss, 1e-7f));
}
__device__ __forceinline__ void gate_chain(float* v, const float* lq, float ssl_q,
                                           const float* lmb, float ssl_b,
                                           float K, float sqrtK, float rsqK, float* sig) {
  float ssv = sq4w(v);
  float m0, ssm;
  expmap0c_(v, ssv, K, sqrtK, rsqK, m0, ssm);
  maddc_(m0, v, ssm, lq, ssl_q, K, sqrtK, rsqK);
  madds_(m0, v, ssm, lmb, ssl_b, K, sqrtK, rsqK);
  float c = logc_(m0, ssm, sqrtK, rsqK);
#pragma unroll
  for (int e = 0; e < 4; ++e) sig[e] = frcp(1.0f + __expf(-c * v[e]));
}

// ---------------- pack weights: uint4[k4*768+col] = 4x half2 ----------------
__global__ void pack_weights(const float* __restrict__ wih, const float* __restrict__ whh,
                             uint4* __restrict__ Pih, uint4* __restrict__ Phh) {
  int idx = blockIdx.x * 256 + threadIdx.x;
  int m   = idx / 24576;
  int rem = idx % 24576;
  int k4  = rem / 768;
  int col = rem % 768;
  int g   = col >> 8;
  int j   = col & 255;
  int gsrc = (g == 0) ? 2 : ((g == 1) ? 0 : 1);
  const float* src = (m == 0) ? wih : whh;
  const float* row = src + (size_t)(gsrc * H1_ + 1 + j) * H1_ + 1 + 8 * k4;
  uint4 o;
  o.x = pkh(row[0], row[1]);
  o.y = pkh(row[2], row[3]);
  o.z = pkh(row[4], row[5]);
  o.w = pkh(row[6], row[7]);
  ((m == 0) ? Pih : Phh)[(size_t)k4 * 768 + col] = o;
}

// ---------------- precompute xU[t*64+b][768] = x_row @ U^T ----------------
__global__ void precompute_xu(const float* __restrict__ x, const uint4* __restrict__ U4,
                              float* __restrict__ xU) {
  __shared__ __align__(16) uint32_t xp[8][128];
  const int tid = threadIdx.x;
  const int row0 = blockIdx.x * 8;
#pragma unroll
  for (int it = 0; it < 4; ++it) {
    int item = it * 256 + tid;
    int r = item >> 7, i = item & 127;
    int row = row0 + r;
    int t = row >> 6, bb = row & 63;
    const float* xr = x + ((size_t)bb * T_ + t) * 256;
    float2 xv = ((const float2*)xr)[i];
    xp[r][i] = pkh(xv.x, xv.y);
  }
  __syncthreads();
  float acc[8][3];
#pragma unroll
  for (int r = 0; r < 8; ++r)
#pragma unroll
    for (int c = 0; c < 3; ++c) acc[r][c] = 0.f;

#pragma unroll 2
  for (int k4 = 0; k4 < 32; ++k4) {
    uint4 w0 = U4[(size_t)k4 * 768 + tid];
    uint4 w1 = U4[(size_t)k4 * 768 + 256 + tid];
    uint4 w2 = U4[(size_t)k4 * 768 + 512 + tid];
#pragma unroll
    for (int r = 0; r < 8; ++r) {
      uint4 gp = ((const uint4*)xp[r])[k4];
      acc[r][0] = fdot2(w0.x, gp.x, acc[r][0]); acc[r][0] = fdot2(w0.y, gp.y, acc[r][0]);
      acc[r][0] = fdot2(w0.z, gp.z, acc[r][0]); acc[r][0] = fdot2(w0.w, gp.w, acc[r][0]);
      acc[r][1] = fdot2(w1.x, gp.x, acc[r][1]); acc[r][1] = fdot2(w1.y, gp.y, acc[r][1]);
      acc[r][1] = fdot2(w1.z, gp.z, acc[r][1]); acc[r][1] = fdot2(w1.w, gp.w, acc[r][1]);
      acc[r][2] = fdot2(w2.x, gp.x, acc[r][2]); acc[r][2] = fdot2(w2.y, gp.y, acc[r][2]);
      acc[r][2] = fdot2(w2.z, gp.z, acc[r][2]); acc[r][2] = fdot2(w2.w, gp.w, acc[r][2]);
    }
  }
#pragma unroll
  for (int r = 0; r < 8; ++r)
#pragma unroll
    for (int c = 0; c < 3; ++c)
      xU[(size_t)(row0 + r) * 768 + c * 256 + tid] = acc[r][c];
}

// ---------------- xUss[row*3+g] = |xU_row_gate|^2 ----------------
__global__ void xuss_kernel(const float* __restrict__ xU, float* __restrict__ xUss) {
  int row  = (blockIdx.x * 256 + threadIdx.x) >> 6;
  int lane = threadIdx.x & 63;
  const float4* base = (const float4*)(xU + (size_t)row * 768);
#pragma unroll
  for (int g = 0; g < 3; ++g) {
    float4 v = base[g * 64 + lane];
    float s = wsum(v.x*v.x + v.y*v.y + v.z*v.z + v.w*v.w);
    if (lane == 0) xUss[(size_t)row * 3 + g] = s;
  }
}

// ---------------- sequential scan, one WG per batch row ----------------
// W_z + W_r held in REGISTERS (split-K x2 over 512 threads: 16+16 uint4/thread);
// W_h staged in LDS. Per-step vector-memory traffic ~= 3 KB xU prefetch only.
__global__ __launch_bounds__(512, 1) void mobius_gru_scan(
    const float* __restrict__ xU, const float* __restrict__ xUss,
    const uint4* __restrict__ W4, const float* __restrict__ bias,
    const float* __restrict__ kin, float* __restrict__ out) {
  __shared__ __align__(16) uint4 LWH[32][256];     // 128 KB: h-gate weights
  __shared__ __align__(16) uint32_t lds_gp[128];   // packed g vector (256 halves)
  __shared__ __align__(16) float lds_v[512];       // r-gate split-K partials
  __shared__ __align__(16) float lds_v2[512];      // z-gate split-K partials
  __shared__ __align__(16) float lds_vh[512];      // h-gate split-K partials
  __shared__ __align__(16) float lds_xu[768];      // lq rows [z | r | h]
  __shared__ __align__(16) float lds_zg[256];      // z gate

  const int tid  = threadIdx.x;
  const int lane = tid & 63;
  const int wave = tid >> 6;
  const int b    = blockIdx.x;
  const int j    = tid & 255;    // output col within gate
  const int kh   = tid >> 8;     // split-K half

  const float kk    = kin[0];
  const float K     = 1.0f / kk;
  const float sqrtK = sqrtf(K);
  const float rsqK  = 1.0f / sqrtK;

  // ---- stage W_h into LDS ----
#pragma unroll
  for (int it = 0; it < 16; ++it) {
    int idx = it * 512 + tid;
    int k4 = idx >> 8, jj = idx & 255;
    LWH[k4][jj] = W4[(size_t)k4 * 768 + 512 + jj];
  }

  // ---- hold W_z, W_r in registers for the whole scan (static indexing only) ----
  uint4 vz[16], vr[16];
#pragma unroll
  for (int i = 0; i < 16; ++i) vz[i] = W4[(size_t)(kh * 16 + i) * 768 + j];
#pragma unroll
  for (int i = 0; i < 16; ++i) vr[i] = W4[(size_t)(kh * 16 + i) * 768 + 256 + j];

  // bias tangent = spatial part; |b|^2 per gate
  float lmeb[3][4]; float sslb[3];
  {
    const int rows[3] = {2, 0, 1};   // z, r, h
#pragma unroll
    for (int g = 0; g < 3; ++g) {
#pragma unroll
      for (int e = 0; e < 4; ++e) lmeb[g][e] = bias[rows[g] * H1_ + 1 + 4 * lane + e];
      sslb[g] = sq4w(lmeb[g]);
    }
  }

  float h0c = 0.f, hs[4] = {0.f, 0.f, 0.f, 0.f}, ssh = 0.f;

  // prefetch t=0 lq row + norms
  float xa, xb, nsv0, nsv1, nsv2;
  {
    const float* xrow = xU + (size_t)b * 768;
    xa = xrow[tid];
    xb = (tid < 256) ? xrow[512 + tid] : 0.f;
    const float* srow = xUss + (size_t)b * 3;
    nsv0 = srow[0]; nsv1 = srow[1]; nsv2 = srow[2];
  }

  __syncthreads();   // staging visible

  float gh[4];       // wave0-valid only

  for (int t = 0; t < T_; ++t) {
    const float s0 = nsv0, s1 = nsv1, s2 = nsv2;

    // phase0: wave0 posts gh = logmap0(h)
    if (wave == 0) {
      logmap0o_(h0c, hs, ssh, sqrtK, rsqK, gh);
      uint2 p; p.x = pkh(gh[0], gh[1]); p.y = pkh(gh[2], gh[3]);
      ((uint2*)lds_gp)[lane] = p;
    }
    LDS_BAR();   // B1

    // ---- phase1: stage lq row; r & z dots from registers (split-K x2) ----
    lds_xu[tid] = xa;
    if (tid < 256) lds_xu[512 + tid] = xb;
    {
      float a0 = 0.f, a1 = 0.f, a2 = 0.f, a3 = 0.f;
      float c0 = 0.f, c1 = 0.f, c2 = 0.f, c3 = 0.f;
#pragma unroll
      for (int i = 0; i < 16; ++i) {
        uint4 gp = ((const uint4*)lds_gp)[kh * 16 + i];
        a0 = fdot2(vr[i].x, gp.x, a0);
        a1 = fdot2(vr[i].y, gp.y, a1);
        a2 = fdot2(vr[i].z, gp.z, a2);
        a3 = fdot2(vr[i].w, gp.w, a3);
        c0 = fdot2(vz[i].x, gp.x, c0);
        c1 = fdot2(vz[i].y, gp.y, c1);
        c2 = fdot2(vz[i].z, gp.z, c2);
        c3 = fdot2(vz[i].w, gp.w, c3);
      }
      lds_v[kh * 256 + j]  = (a0 + a1) + (a2 + a3);
      lds_v2[kh * 256 + j] = (c0 + c1) + (c2 + c3);
    }
    if (t + 1 < T_) {   // next-step prefetch (in flight across barriers)
      const float* nx = xU + (size_t)((t + 1) * B_ + b) * 768;
      xa = nx[tid];
      xb = (tid < 256) ? nx[512 + tid] : 0.f;
      const float* srow = xUss + (size_t)((t + 1) * B_ + b) * 3;
      nsv0 = srow[0]; nsv1 = srow[1]; nsv2 = srow[2];
    }
    LDS_BAR();   // B2

    if (wave == 0) {
      // ---- r-gate chain (SIMD0) ----
      float v[4], xv[4];
      {
        float4 pa = ((const float4*)lds_v)[lane];
        float4 pb = ((const float4*)lds_v)[64 + lane];
        v[0] = pa.x + pb.x; v[1] = pa.y + pb.y; v[2] = pa.z + pb.z; v[3] = pa.w + pb.w;
      }
      { float4 t4 = ((const float4*)lds_xu)[64 + lane]; xv[0]=t4.x; xv[1]=t4.y; xv[2]=t4.z; xv[3]=t4.w; }
      float rg[4];
      gate_chain(v, xv, s1, lmeb[1], sslb[1], K, sqrtK, rsqK, rg);
      // lrh = logmap0(expmap0(r*gh)) == r*gh
      uint2 p;
      p.x = pkh(rg[0] * gh[0], rg[1] * gh[1]);
      p.y = pkh(rg[2] * gh[2], rg[3] * gh[3]);
      ((uint2*)lds_gp)[lane] = p;
    } else if (wave == 1) {
      // ---- z-gate chain (SIMD1, parallel) ----
      float v[4], xv[4];
      {
        float4 pa = ((const float4*)lds_v2)[lane];
        float4 pb = ((const float4*)lds_v2)[64 + lane];
        v[0] = pa.x + pb.x; v[1] = pa.y + pb.y; v[2] = pa.z + pb.z; v[3] = pa.w + pb.w;
      }
      { float4 t4 = ((const float4*)lds_xu)[lane]; xv[0]=t4.x; xv[1]=t4.y; xv[2]=t4.z; xv[3]=t4.w; }
      float zg[4];
      gate_chain(v, xv, s0, lmeb[0], sslb[0], K, sqrtK, rsqK, zg);
      float4 z4 = {zg[0], zg[1], zg[2], zg[3]};
      ((float4*)lds_zg)[lane] = z4;
    }
    LDS_BAR();   // B3

    // ---- phase3: GEMV-h from LDS weights, split-K x2 ----
    {
      const uint4* wl = &LWH[kh * 16][j];
      float a0 = 0.f, a1 = 0.f, a2 = 0.f, a3 = 0.f;
#pragma unroll
      for (int i = 0; i < 16; ++i) {
        uint4 w  = wl[(size_t)i * 256];
        uint4 gp = ((const uint4*)lds_gp)[kh * 16 + i];
        a0 = fdot2(w.x, gp.x, a0);
        a1 = fdot2(w.y, gp.y, a1);
        a2 = fdot2(w.z, gp.z, a2);
        a3 = fdot2(w.w, gp.w, a3);
      }
      lds_vh[kh * 256 + j] = (a0 + a1) + (a2 + a3);
    }
    LDS_BAR();   // B4

    if (wave == 0) {
      // ---- h_tilde chain ----
      float t0, ts[4], sst;
      {
        float4 pa = ((const float4*)lds_vh)[lane];
        float4 pb = ((const float4*)lds_vh)[64 + lane];
        ts[0] = pa.x + pb.x; ts[1] = pa.y + pb.y; ts[2] = pa.z + pb.z; ts[3] = pa.w + pb.w;
        float xv[4];
        { float4 t4 = ((const float4*)lds_xu)[128 + lane]; xv[0]=t4.x; xv[1]=t4.y; xv[2]=t4.z; xv[3]=t4.w; }
        float ssv = sq4w(ts);
        expmap0c_(ts, ssv, K, sqrtK, rsqK, t0, sst);
        maddc_(t0, ts, sst, xv, s2, K, sqrtK, rsqK);
        madds_(t0, ts, sst, lmeb[2], sslb[2], K, sqrtK, rsqK);
      }

      // ---- delta_h = mobius_add(proj(-hx), h_tilde) ----
      float n0, ns[4], ssn = ssh;
#pragma unroll
      for (int e = 0; e < 4; ++e) ns[e] = -hs[e];
      n0 = sqrtf(fmaxf(K + ssh, 1e-7f));
      float lt[4], sslt;
      logmap0c_(t0, ts, sst, K, sqrtK, rsqK, lt, sslt);
      maddc_(n0, ns, ssn, lt, sslt, K, sqrtK, rsqK);

      // ---- h_new = expmap(ptransp0(hx, z*logmap0(delta_h)), hx) ----
      float ld[4];
      logmap0o_(n0, ns, ssn, sqrtK, rsqK, ld);
      float uu[4];
      {
        float4 z4 = ((const float4*)lds_zg)[lane];
        uu[0] = z4.x * ld[0]; uu[1] = z4.y * ld[1]; uu[2] = z4.z * ld[2]; uu[3] = z4.w * ld[3];
      }
      float ssuu = sq4w(uu);
      maddc_(h0c, hs, ssh, uu, ssuu, K, sqrtK, rsqK);

      float* orow = out + (size_t)(t * B_ + b) * H1_;
      if (lane == 0) orow[0] = h0c;
#pragma unroll
      for (int e = 0; e < 4; ++e) orow[1 + 4 * lane + e] = hs[e];
    }
  }

  if (wave == 0) {
    float4 hv = {hs[0], hs[1], hs[2], hs[3]};
    ((float4*)(out + (size_t)T_ * B_ * H1_ + (size_t)b * 256))[lane] = hv;
  }
}

// ---------------- launch ----------------
extern "C" void kernel_launch(void* const* d_in, const int* in_sizes, int n_in,
                              void* d_out, int out_size, void* d_ws, size_t ws_size,
                              hipStream_t stream) {
  const float* x    = (const float*)d_in[0];
  const float* k    = (const float*)d_in[1];
  const float* wih  = (const float*)d_in[2];
  const float* whh  = (const float*)d_in[3];
  const float* bias = (const float*)d_in[4];
  float* out = (float*)d_out;

  // ws: Pih (24576 uint4, overlaid by xUss) | Phh (24576 uint4) | xU (32768*768 f)
  uint4* Pih = (uint4*)d_ws;
  uint4* Phh = Pih + 24576;
  float* xU  = (float*)(Phh + 24576);
  float* xUss = (float*)Pih;   // Pih dead after precompute_xu

  pack_weights<<<192, 256, 0, stream>>>(wih, whh, Pih, Phh);
  precompute_xu<<<4096, 256, 0, stream>>>(x, Pih, xU);
  xuss_kernel<<<8192, 256, 0, stream>>>(xU, xUss);
  mobius_gru_scan<<<B_, 512, 0, stream>>>(xU, xUss, Phh, bias, k, out);
}